// Round 1
// baseline (1577.122 us; speedup 1.0000x reference)
//
#include <hip/hip_runtime.h>
#include <math.h>
#include <stdint.h>

#define Bn 2
#define Ln 2048
#define Dn 1024
#define Hn 16
#define DHn 64
#define Un 1228
#define SCALE 0.125f

// ---------------- generic GEMM: C[M,N] = A[M,K] @ W[K,N] + bias ----------------
// 64x64 tile, 256 threads, 4x4 microtile, K-step 16.
__global__ __launch_bounds__(256) void gemm_bias_k(
    const float* __restrict__ A, const float* __restrict__ W,
    const float* __restrict__ bias, float* __restrict__ C,
    int M, int N, int Kd) {
  __shared__ float As[64][20];   // [m][kk], pad 16->20 to break ty-stride conflicts
  __shared__ float Ws[16][64];   // [kk][n]
  const int t = threadIdx.x;
  const int tx = t & 15, ty = t >> 4;
  const int n0 = blockIdx.x * 64, m0 = blockIdx.y * 64;
  const int ea = t * 4;
  const int am = ea >> 4, ak = ea & 15;   // A-tile element
  const int wk = ea >> 6, wn = ea & 63;   // W-tile element
  float acc[4][4] = {};
  for (int k0 = 0; k0 < Kd; k0 += 16) {
    float4 a4 = *reinterpret_cast<const float4*>(&A[(size_t)(m0 + am) * Kd + k0 + ak]);
    float4 w4 = *reinterpret_cast<const float4*>(&W[(size_t)(k0 + wk) * N + n0 + wn]);
    *reinterpret_cast<float4*>(&As[am][ak]) = a4;
    *reinterpret_cast<float4*>(&Ws[wk][wn]) = w4;
    __syncthreads();
#pragma unroll
    for (int kk0 = 0; kk0 < 16; kk0 += 4) {
      float a[4][4], b[4][4];
#pragma unroll
      for (int i = 0; i < 4; ++i) {
        float4 v = *reinterpret_cast<const float4*>(&As[ty * 4 + i][kk0]);
        a[i][0] = v.x; a[i][1] = v.y; a[i][2] = v.z; a[i][3] = v.w;
      }
#pragma unroll
      for (int q = 0; q < 4; ++q) {
        float4 v = *reinterpret_cast<const float4*>(&Ws[kk0 + q][tx * 4]);
        b[q][0] = v.x; b[q][1] = v.y; b[q][2] = v.z; b[q][3] = v.w;
      }
#pragma unroll
      for (int q = 0; q < 4; ++q)
#pragma unroll
        for (int i = 0; i < 4; ++i)
#pragma unroll
          for (int j = 0; j < 4; ++j)
            acc[i][j] = fmaf(a[i][q], b[q][j], acc[i][j]);
    }
    __syncthreads();
  }
  float4 bias4 = *reinterpret_cast<const float4*>(&bias[n0 + tx * 4]);
#pragma unroll
  for (int i = 0; i < 4; ++i) {
    float4 o;
    o.x = acc[i][0] + bias4.x; o.y = acc[i][1] + bias4.y;
    o.z = acc[i][2] + bias4.z; o.w = acc[i][3] + bias4.w;
    *reinterpret_cast<float4*>(&C[(size_t)(m0 + ty * 4 + i) * N + n0 + tx * 4]) = o;
  }
}

// ------------- per-row score stats: max and (max - mean) over all keys -------------
// Block: 64 q-rows x (loop over 32 key-tiles of 64). grid = (L/64, B*H)
__global__ __launch_bounds__(256) void attn_stats(
    const float* __restrict__ Q, const float* __restrict__ K,
    float* __restrict__ row_max, float* __restrict__ row_spars) {
  __shared__ float Qs[64][68];    // [m][d], scaled
  __shared__ float Kst[64][68];   // [d][n] (transposed K tile)
  __shared__ float redm[64][17];
  __shared__ float reds[64][17];
  const int t = threadIdx.x;
  const int tx = t & 15, ty = t >> 4;
  const int bh = blockIdx.y;
  const int b = bh >> 4, h = bh & 15;
  const int q0 = blockIdx.x * 64;
  const size_t baseQ = ((size_t)b * Ln + q0) * Dn + h * DHn;
#pragma unroll
  for (int chunk = 0; chunk < 4; ++chunk) {
    int e = chunk * 1024 + t * 4;
    int m = e >> 6, d = e & 63;
    float4 v = *reinterpret_cast<const float4*>(&Q[baseQ + (size_t)m * Dn + d]);
    v.x *= SCALE; v.y *= SCALE; v.z *= SCALE; v.w *= SCALE;
    *reinterpret_cast<float4*>(&Qs[m][d]) = v;
  }
  float mx[4], sm[4];
#pragma unroll
  for (int i = 0; i < 4; ++i) { mx[i] = -1e30f; sm[i] = 0.f; }

  for (int kt = 0; kt < Ln / 64; ++kt) {
    __syncthreads();   // also covers initial Qs readiness
    const size_t baseK = ((size_t)b * Ln + kt * 64) * Dn + h * DHn;
#pragma unroll
    for (int chunk = 0; chunk < 4; ++chunk) {
      int e = chunk * 1024 + t * 4;
      int n = e >> 6, d = e & 63;
      float4 v = *reinterpret_cast<const float4*>(&K[baseK + (size_t)n * Dn + d]);
      Kst[d + 0][n] = v.x; Kst[d + 1][n] = v.y; Kst[d + 2][n] = v.z; Kst[d + 3][n] = v.w;
    }
    __syncthreads();
    float acc[4][4] = {};
#pragma unroll
    for (int d0 = 0; d0 < 64; d0 += 4) {
      float a[4][4], bb[4][4];
#pragma unroll
      for (int i = 0; i < 4; ++i) {
        float4 v = *reinterpret_cast<const float4*>(&Qs[ty * 4 + i][d0]);
        a[i][0] = v.x; a[i][1] = v.y; a[i][2] = v.z; a[i][3] = v.w;
      }
#pragma unroll
      for (int q = 0; q < 4; ++q) {
        float4 v = *reinterpret_cast<const float4*>(&Kst[d0 + q][tx * 4]);
        bb[q][0] = v.x; bb[q][1] = v.y; bb[q][2] = v.z; bb[q][3] = v.w;
      }
#pragma unroll
      for (int q = 0; q < 4; ++q)
#pragma unroll
        for (int i = 0; i < 4; ++i)
#pragma unroll
          for (int j = 0; j < 4; ++j)
            acc[i][j] = fmaf(a[i][q], bb[q][j], acc[i][j]);
    }
#pragma unroll
    for (int i = 0; i < 4; ++i)
#pragma unroll
      for (int j = 0; j < 4; ++j) {
        mx[i] = fmaxf(mx[i], acc[i][j]);
        sm[i] += acc[i][j];
      }
  }
#pragma unroll
  for (int i = 0; i < 4; ++i) {
    redm[ty * 4 + i][tx] = mx[i];
    reds[ty * 4 + i][tx] = sm[i];
  }
  __syncthreads();
  if (t < 64) {
    float m = -1e30f, s = 0.f;
#pragma unroll
    for (int xk = 0; xk < 16; ++xk) { m = fmaxf(m, redm[t][xk]); s += reds[t][xk]; }
    row_max[(size_t)bh * Ln + q0 + t] = m;
    row_spars[(size_t)bh * Ln + q0 + t] = m - s * (1.0f / Ln);
  }
}

// ------------- top-U selection via in-LDS bitonic sort of 2048 u64 keys -------------
__global__ __launch_bounds__(256) void topk_sel(
    const float* __restrict__ spars, int* __restrict__ top_idx) {
  __shared__ unsigned long long keys[Ln];   // 16 KB
  const int t = threadIdx.x;
  const int bh = blockIdx.x;
  for (int i = t; i < Ln; i += 256) {
    unsigned u = __float_as_uint(spars[(size_t)bh * Ln + i]);
    u = (u & 0x80000000u) ? ~u : (u | 0x80000000u);  // ascending-sortable
    u = ~u;                                          // descending value
    keys[i] = ((unsigned long long)u << 32) | (unsigned)i;  // asc idx tiebreak
  }
  __syncthreads();
  for (unsigned k = 2; k <= Ln; k <<= 1) {
    for (unsigned j = k >> 1; j > 0; j >>= 1) {
#pragma unroll
      for (int p = 0; p < Ln / 256; ++p) {
        int i = p * 256 + t;
        int ixj = i ^ (int)j;
        if (ixj > i) {
          unsigned long long a = keys[i], bb = keys[ixj];
          bool up = ((i & (int)k) == 0);
          if ((a > bb) == up) { keys[i] = bb; keys[ixj] = a; }
        }
      }
      __syncthreads();
    }
  }
  for (int u = t; u < Un; u += 256)
    top_idx[(size_t)bh * Un + u] = (int)(keys[u] & 0xFFFFFFFFu);
}

// ------------- attention on selected rows, scatter into attn_out -------------
// Block: 32 selected queries x loop over 32 key-tiles of 64. grid = (ceil(U/32), B*H)
__global__ __launch_bounds__(256) void attn_sel(
    const float* __restrict__ Q, const float* __restrict__ K,
    const float* __restrict__ V, const int* __restrict__ top_idx,
    const float* __restrict__ row_max, float* __restrict__ attn_out) {
  __shared__ float Qs[32][68];   // scaled selected-Q rows
  __shared__ float Kst[64][68];  // [d][n]
  __shared__ float Vs[64][68];   // [n][d]
  __shared__ float Ps[32][68];   // exp(scores - rowmax)
  __shared__ float redd[32][17];
  __shared__ float dsum[32];
  __shared__ int qidx[32];
  __shared__ float rms[32];
  const int t = threadIdx.x;
  const int tx = t & 15, ty = t >> 4;
  const int bh = blockIdx.y;
  const int b = bh >> 4, h = bh & 15;
  const int u0 = blockIdx.x * 32;
  const int nrows = (Un - u0 < 32) ? (Un - u0) : 32;
  if (t < 32) {
    int qi = (t < nrows) ? top_idx[(size_t)bh * Un + u0 + t] : 0;
    qidx[t] = qi;
    rms[t] = row_max[(size_t)bh * Ln + qi];
  }
  __syncthreads();
#pragma unroll
  for (int chunk = 0; chunk < 2; ++chunk) {
    int e = chunk * 1024 + t * 4;
    int m = e >> 6, d = e & 63;
    int qi = qidx[m];
    float4 v = *reinterpret_cast<const float4*>(&Q[((size_t)b * Ln + qi) * Dn + h * DHn + d]);
    v.x *= SCALE; v.y *= SCALE; v.z *= SCALE; v.w *= SCALE;
    *reinterpret_cast<float4*>(&Qs[m][d]) = v;
  }
  float rm[2];
  rm[0] = rms[ty * 2];
  rm[1] = rms[ty * 2 + 1];
  float oacc[2][4] = {};
  float dacc[2] = {0.f, 0.f};

  for (int kt = 0; kt < Ln / 64; ++kt) {
    __syncthreads();
    const size_t baseK = ((size_t)b * Ln + kt * 64) * Dn + h * DHn;
#pragma unroll
    for (int chunk = 0; chunk < 4; ++chunk) {
      int e = chunk * 1024 + t * 4;
      int n = e >> 6, d = e & 63;
      float4 kv = *reinterpret_cast<const float4*>(&K[baseK + (size_t)n * Dn + d]);
      Kst[d + 0][n] = kv.x; Kst[d + 1][n] = kv.y; Kst[d + 2][n] = kv.z; Kst[d + 3][n] = kv.w;
      float4 vv = *reinterpret_cast<const float4*>(&V[baseK + (size_t)n * Dn + d]);
      *reinterpret_cast<float4*>(&Vs[n][d]) = vv;
    }
    __syncthreads();
    // scores: rows m = ty*2+i, keys n = tx*4+j
    float sacc[2][4] = {};
#pragma unroll
    for (int d0 = 0; d0 < 64; d0 += 4) {
      float a[2][4], bb[4][4];
#pragma unroll
      for (int i = 0; i < 2; ++i) {
        float4 v = *reinterpret_cast<const float4*>(&Qs[ty * 2 + i][d0]);
        a[i][0] = v.x; a[i][1] = v.y; a[i][2] = v.z; a[i][3] = v.w;
      }
#pragma unroll
      for (int q = 0; q < 4; ++q) {
        float4 v = *reinterpret_cast<const float4*>(&Kst[d0 + q][tx * 4]);
        bb[q][0] = v.x; bb[q][1] = v.y; bb[q][2] = v.z; bb[q][3] = v.w;
      }
#pragma unroll
      for (int q = 0; q < 4; ++q)
#pragma unroll
        for (int i = 0; i < 2; ++i)
#pragma unroll
          for (int j = 0; j < 4; ++j)
            sacc[i][j] = fmaf(a[i][q], bb[q][j], sacc[i][j]);
    }
#pragma unroll
    for (int i = 0; i < 2; ++i)
#pragma unroll
      for (int j = 0; j < 4; ++j) {
        float p = expf(sacc[i][j] - rm[i]);
        dacc[i] += p;
        Ps[ty * 2 + i][tx * 4 + j] = p;
      }
    __syncthreads();
    // O += P @ V : rows m = ty*2+i, dims d = tx*4+j
#pragma unroll
    for (int k0 = 0; k0 < 64; k0 += 4) {
      float pp[2][4], vv4[4][4];
#pragma unroll
      for (int i = 0; i < 2; ++i) {
        float4 v = *reinterpret_cast<const float4*>(&Ps[ty * 2 + i][k0]);
        pp[i][0] = v.x; pp[i][1] = v.y; pp[i][2] = v.z; pp[i][3] = v.w;
      }
#pragma unroll
      for (int q = 0; q < 4; ++q) {
        float4 v = *reinterpret_cast<const float4*>(&Vs[k0 + q][tx * 4]);
        vv4[q][0] = v.x; vv4[q][1] = v.y; vv4[q][2] = v.z; vv4[q][3] = v.w;
      }
#pragma unroll
      for (int q = 0; q < 4; ++q)
#pragma unroll
        for (int i = 0; i < 2; ++i)
#pragma unroll
          for (int j = 0; j < 4; ++j)
            oacc[i][j] = fmaf(pp[i][q], vv4[q][j], oacc[i][j]);
    }
  }
  __syncthreads();
#pragma unroll
  for (int i = 0; i < 2; ++i) redd[ty * 2 + i][tx] = dacc[i];
  __syncthreads();
  if (t < 32) {
    float s = 0.f;
#pragma unroll
    for (int xk = 0; xk < 16; ++xk) s += redd[t][xk];
    dsum[t] = s;
  }
  __syncthreads();
#pragma unroll
  for (int i = 0; i < 2; ++i) {
    int m = ty * 2 + i;
    if (u0 + m < Un) {
      float dinv = 1.0f / dsum[m];
      int qi = qidx[m];
      float4 o;
      o.x = oacc[i][0] * dinv; o.y = oacc[i][1] * dinv;
      o.z = oacc[i][2] * dinv; o.w = oacc[i][3] * dinv;
      *reinterpret_cast<float4*>(&attn_out[((size_t)b * Ln + qi) * Dn + h * DHn + tx * 4]) = o;
    }
  }
}

extern "C" void kernel_launch(void* const* d_in, const int* in_sizes, int n_in,
                              void* d_out, int out_size, void* d_ws, size_t ws_size,
                              hipStream_t stream) {
  (void)in_sizes; (void)n_in; (void)out_size; (void)ws_size;
  const float* x  = (const float*)d_in[0];
  const float* Wq = (const float*)d_in[1];
  const float* bq = (const float*)d_in[2];
  const float* Wk = (const float*)d_in[3];
  const float* bk = (const float*)d_in[4];
  const float* Wv = (const float*)d_in[5];
  const float* bv = (const float*)d_in[6];
  const float* Wo = (const float*)d_in[7];
  const float* bo = (const float*)d_in[8];
  float* out = (float*)d_out;

  float* ws = (float*)d_ws;
  const size_t NE = (size_t)Bn * Ln * Dn;   // 4M floats
  float* Qb = ws;
  float* Kb = Qb + NE;
  float* Vb = Kb + NE;
  float* AO = Vb + NE;
  float* rowmax = AO + NE;
  float* spars  = rowmax + (size_t)Bn * Hn * Ln;
  int*   topi   = (int*)(spars + (size_t)Bn * Hn * Ln);

  dim3 blk(256);
  dim3 gg(Dn / 64, (Bn * Ln) / 64);
  hipLaunchKernelGGL(gemm_bias_k, gg, blk, 0, stream, x, Wq, bq, Qb, Bn * Ln, Dn, Dn);
  hipLaunchKernelGGL(gemm_bias_k, gg, blk, 0, stream, x, Wk, bk, Kb, Bn * Ln, Dn, Dn);
  hipLaunchKernelGGL(gemm_bias_k, gg, blk, 0, stream, x, Wv, bv, Vb, Bn * Ln, Dn, Dn);
  hipLaunchKernelGGL(attn_stats, dim3(Ln / 64, Bn * Hn), blk, 0, stream, Qb, Kb, rowmax, spars);
  hipLaunchKernelGGL(topk_sel, dim3(Bn * Hn), blk, 0, stream, spars, topi);
  hipMemsetAsync(AO, 0, NE * sizeof(float), stream);
  hipLaunchKernelGGL(attn_sel, dim3((Un + 31) / 32, Bn * Hn), blk, 0, stream,
                     Qb, Kb, Vb, topi, rowmax, AO);
  hipLaunchKernelGGL(gemm_bias_k, gg, blk, 0, stream, AO, Wo, bo, out, Bn * Ln, Dn, Dn);
}

// Round 3
// 956.517 us; speedup vs baseline: 1.6488x; 1.6488x over previous
//
#include <hip/hip_runtime.h>
#include <math.h>
#include <stdint.h>

#define Bn 2
#define Ln 2048
#define Dn 1024
#define Hn 16
#define DHn 64
#define Un 1228
#define BHn (Bn*Hn)
#define SCALE 0.125f
// pre-split power-of-2 scales (dodge fp16 subnormal flush on lo terms)
#define SXf 16.0f     // x
#define SWf 256.0f    // all W
#define SQf 16.0f     // Q, K
#define SVf 16.0f     // V
#define SPf 16.0f     // softmax P
#define SAf 256.0f    // attention out AO
#define ESC_PROJ (1.0f / 4096.0f)    // 1/(SX*SW)
#define ESC_OUT  (1.0f / 65536.0f)   // 1/(SA*SW)
#define PSC (SCALE / 256.0f)         // score unscale: 1/(SQ*SQ) * SCALE

typedef _Float16 f16;
typedef __attribute__((ext_vector_type(8))) _Float16 f16x8;
typedef __attribute__((ext_vector_type(4))) float f32x4;
struct h4s { f16 x, y, z, w; };

__device__ __forceinline__ void splitf16(float f, f16& hi, f16& lo) {
  hi = (f16)f;                 // RTNE
  lo = (f16)(f - (float)hi);   // residual, captures ~22 mantissa bits total
}

// async global->LDS, 16B per lane (wave-uniform base + lane*16)
__device__ __forceinline__ void gl_lds16(const void* g, void* l) {
  __builtin_amdgcn_global_load_lds(
      (const __attribute__((address_space(1))) void*)g,
      (__attribute__((address_space(3))) void*)l, 16, 0, 0);
}

#define MFMA(a, b, c) __builtin_amdgcn_mfma_f32_16x16x32_f16((a), (b), (c), 0, 0, 0)

// ---------------- split x*16 -> xh, xl ----------------
__global__ __launch_bounds__(256) void split_kernel(
    const float* __restrict__ in, f16* __restrict__ oh, f16* __restrict__ ol, int n4) {
  int i = blockIdx.x * 256 + threadIdx.x;
  if (i >= n4) return;
  float4 v = ((const float4*)in)[i];
  h4s h, l;
  splitf16(v.x * SXf, h.x, l.x); splitf16(v.y * SXf, h.y, l.y);
  splitf16(v.z * SXf, h.z, l.z); splitf16(v.w * SXf, h.w, l.w);
  ((h4s*)oh)[i] = h; ((h4s*)ol)[i] = l;
}

// ---------------- transpose + split W*256: W[k][n] -> Wt[n][k] hi/lo ----------------
__global__ __launch_bounds__(256) void tsplit_w(
    const float* __restrict__ in, f16* __restrict__ oh, f16* __restrict__ ol) {
  __shared__ float ts[64][65];
  const int t = threadIdx.x;
  const int r0 = blockIdx.x * 64, c0 = blockIdx.y * 64;
#pragma unroll
  for (int c = 0; c < 4; ++c) {
    int f = (c * 256 + t) * 4; int row = f >> 6, col = f & 63;
    float4 v = *(const float4*)&in[(size_t)(r0 + row) * Dn + c0 + col];
    ts[row][col] = v.x; ts[row][col + 1] = v.y; ts[row][col + 2] = v.z; ts[row][col + 3] = v.w;
  }
  __syncthreads();
#pragma unroll
  for (int c = 0; c < 4; ++c) {
    int f = (c * 256 + t) * 4; int crow = f >> 6, rcol = f & 63;
    h4s h, l;
    splitf16(ts[rcol + 0][crow] * SWf, h.x, l.x);
    splitf16(ts[rcol + 1][crow] * SWf, h.y, l.y);
    splitf16(ts[rcol + 2][crow] * SWf, h.z, l.z);
    splitf16(ts[rcol + 3][crow] * SWf, h.w, l.w);
    size_t o = (size_t)(c0 + crow) * Dn + r0 + rcol;
    *(h4s*)&oh[o] = h; *(h4s*)&ol[o] = l;
  }
}

// ---------------- transpose + split V*16: V[b,l,D] -> Vt[bh*64+d][L] hi/lo ----------------
__global__ __launch_bounds__(256) void tsplit_v(
    const float* __restrict__ Vf, f16* __restrict__ oh, f16* __restrict__ ol) {
  __shared__ float ts[64][65];
  const int t = threadIdx.x;
  const int l0 = blockIdx.x * 64;
  const int bh = blockIdx.y, b = bh >> 4, h = bh & 15;
#pragma unroll
  for (int c = 0; c < 4; ++c) {
    int f = (c * 256 + t) * 4; int lrow = f >> 6, dcol = f & 63;
    float4 v = *(const float4*)&Vf[((size_t)b * Ln + l0 + lrow) * Dn + h * DHn + dcol];
    ts[lrow][dcol] = v.x; ts[lrow][dcol + 1] = v.y; ts[lrow][dcol + 2] = v.z; ts[lrow][dcol + 3] = v.w;
  }
  __syncthreads();
#pragma unroll
  for (int c = 0; c < 4; ++c) {
    int f = (c * 256 + t) * 4; int drow = f >> 6, lcol = f & 63;
    h4s h4, l4;
    splitf16(ts[lcol + 0][drow] * SVf, h4.x, l4.x);
    splitf16(ts[lcol + 1][drow] * SVf, h4.y, l4.y);
    splitf16(ts[lcol + 2][drow] * SVf, h4.z, l4.z);
    splitf16(ts[lcol + 3][drow] * SVf, h4.w, l4.w);
    size_t o = ((size_t)bh * DHn + drow) * Ln + l0 + lcol;
    *(h4s*)&oh[o] = h4; *(h4s*)&ol[o] = l4;
  }
}

// ---------------- split-fp16 MFMA GEMM: C = (A @ Bt^T)*escale + bias ----------------
// A hi/lo [M][K], Bt hi/lo [N][K]; 128x128 tile, BK=32, 4 waves (2x2), 4x4 frags/wave.
__global__ __launch_bounds__(256) void gemm_split(
    const f16* __restrict__ Ah, const f16* __restrict__ Al,
    const f16* __restrict__ Bth, const f16* __restrict__ Btl,
    const float* __restrict__ bias, float escale, float osplit,
    float* __restrict__ Cf, f16* __restrict__ Ch, f16* __restrict__ Cl,
    int M, int N, int K) {
  __shared__ f16 sAh[128 * 32], sAl[128 * 32], sBh[128 * 32], sBl[128 * 32];
  const int t = threadIdx.x;
  const int w = t >> 6, lane = t & 63, lm = lane & 15, q = lane >> 4;
  const int wr = w >> 1, wc = w & 1;
  const int n0 = blockIdx.x * 128, m0 = blockIdx.y * 128;
  f32x4 acc[4][4] = {};
  for (int k0 = 0; k0 < K; k0 += 32) {
    const f16* s0 = Ah + (size_t)m0 * K + k0;
    const f16* s1 = Al + (size_t)m0 * K + k0;
    const f16* s2 = Bth + (size_t)n0 * K + k0;
    const f16* s3 = Btl + (size_t)n0 * K + k0;
#pragma unroll
    for (int c = 0; c < 2; ++c) {
      int f = (c * 256 + t) * 8; int row = f >> 5, col = f & 31;
      size_t go = (size_t)row * K + col;
      gl_lds16(s0 + go, &sAh[f]);
      gl_lds16(s1 + go, &sAl[f]);
      gl_lds16(s2 + go, &sBh[f]);
      gl_lds16(s3 + go, &sBl[f]);
    }
    __syncthreads();
    f16x8 a_h[4], a_l[4], b_h[4], b_l[4];
#pragma unroll
    for (int mi = 0; mi < 4; ++mi) {
      int r = (wr * 64 + mi * 16 + lm) * 32 + q * 8;
      a_h[mi] = *(const f16x8*)&sAh[r];
      a_l[mi] = *(const f16x8*)&sAl[r];
    }
#pragma unroll
    for (int ni = 0; ni < 4; ++ni) {
      int r = (wc * 64 + ni * 16 + lm) * 32 + q * 8;
      b_h[ni] = *(const f16x8*)&sBh[r];
      b_l[ni] = *(const f16x8*)&sBl[r];
    }
#pragma unroll
    for (int mi = 0; mi < 4; ++mi)
#pragma unroll
      for (int ni = 0; ni < 4; ++ni) {
        acc[mi][ni] = MFMA(a_h[mi], b_h[ni], acc[mi][ni]);
        acc[mi][ni] = MFMA(a_h[mi], b_l[ni], acc[mi][ni]);
        acc[mi][ni] = MFMA(a_l[mi], b_h[ni], acc[mi][ni]);
      }
    __syncthreads();
  }
#pragma unroll
  for (int mi = 0; mi < 4; ++mi)
#pragma unroll
    for (int ni = 0; ni < 4; ++ni) {
      int gcol = n0 + wc * 64 + ni * 16 + lm;
      float bv = bias[gcol];
#pragma unroll
      for (int r = 0; r < 4; ++r) {
        int grow = m0 + wr * 64 + mi * 16 + q * 4 + r;
        float v = acc[mi][ni][r] * escale + bv;
        size_t o = (size_t)grow * N + gcol;
        if (Cf) Cf[o] = v;
        if (Ch) { f16 hh, ll; splitf16(v * osplit, hh, ll); Ch[o] = hh; Cl[o] = ll; }
      }
    }
}

// ---------------- ksum[bh][d] = sum_l K'[b,l,h*64+d] (scaled-by-SQ units) ----------------
__global__ __launch_bounds__(256) void ksum_kernel(
    const f16* __restrict__ Kh, const f16* __restrict__ Kl, float* __restrict__ ksum) {
  __shared__ float red[4][64];
  const int t = threadIdx.x, d = t & 63, seg = t >> 6;
  const int bh = blockIdx.x, b = bh >> 4, h = bh & 15;
  float s = 0.f;
  for (int l = seg * 512; l < (seg + 1) * 512; ++l) {
    size_t o = ((size_t)b * Ln + l) * Dn + h * DHn + d;
    s += (float)Kh[o] + (float)Kl[o];
  }
  red[seg][d] = s;
  __syncthreads();
  if (t < 64) ksum[bh * DHn + t] = red[0][t] + red[1][t] + red[2][t] + red[3][t];
}

// ---------------- stats: approx row max (MFMA) + spars = max - mean ----------------
__global__ __launch_bounds__(256) void attn_stats_mfma(
    const f16* __restrict__ Qh, const f16* __restrict__ Ql,
    const f16* __restrict__ Kh, const f16* __restrict__ Kl,
    const float* __restrict__ ksum,
    float* __restrict__ row_max, float* __restrict__ spars) {
  __shared__ f16 sQh[128 * 64], sQl[128 * 64], sKh[128 * 64], sKl[128 * 64];
  __shared__ float redm[128][5];
  const int t = threadIdx.x;
  const int w = t >> 6, lane = t & 63, lm = lane & 15, q = lane >> 4;
  const int bh = blockIdx.y, b = bh >> 4, h = bh & 15;
  const int q0 = blockIdx.x * 128;
  const f16* qsh = Qh + ((size_t)b * Ln + q0) * Dn + h * DHn;
  const f16* qsl = Ql + ((size_t)b * Ln + q0) * Dn + h * DHn;
#pragma unroll
  for (int c = 0; c < 4; ++c) {
    int f = (c * 256 + t) * 8; int row = f >> 6, col = f & 63;
    size_t go = (size_t)row * Dn + col;
    gl_lds16(qsh + go, &sQh[f]);
    gl_lds16(qsl + go, &sQl[f]);
  }
  float rmax[8][4];
#pragma unroll
  for (int mi = 0; mi < 8; ++mi)
#pragma unroll
    for (int r = 0; r < 4; ++r) rmax[mi][r] = -1e30f;

  for (int kt = 0; kt < Ln / 128; ++kt) {
    __syncthreads();
    const f16* ksh = Kh + ((size_t)b * Ln + kt * 128) * Dn + h * DHn;
    const f16* ksl = Kl + ((size_t)b * Ln + kt * 128) * Dn + h * DHn;
#pragma unroll
    for (int c = 0; c < 4; ++c) {
      int f = (c * 256 + t) * 8; int row = f >> 6, col = f & 63;
      size_t go = (size_t)row * Dn + col;
      gl_lds16(ksh + go, &sKh[f]);
      gl_lds16(ksl + go, &sKl[f]);
    }
    __syncthreads();
#pragma unroll
    for (int ni = 0; ni < 2; ++ni) {
      int bcol = (w * 2 + ni) * 16;
      f16x8 b_h[2], b_l[2];
#pragma unroll
      for (int ks = 0; ks < 2; ++ks) {
        int r = (bcol + lm) * 64 + ks * 32 + q * 8;
        b_h[ks] = *(const f16x8*)&sKh[r];
        b_l[ks] = *(const f16x8*)&sKl[r];
      }
#pragma unroll
      for (int mi = 0; mi < 8; ++mi) {
        f32x4 acc = {0.f, 0.f, 0.f, 0.f};
#pragma unroll
        for (int ks = 0; ks < 2; ++ks) {
          int r = (mi * 16 + lm) * 64 + ks * 32 + q * 8;
          f16x8 a_h = *(const f16x8*)&sQh[r];
          f16x8 a_l = *(const f16x8*)&sQl[r];
          acc = MFMA(a_h, b_h[ks], acc);
          acc = MFMA(a_h, b_l[ks], acc);
          acc = MFMA(a_l, b_h[ks], acc);
        }
#pragma unroll
        for (int r = 0; r < 4; ++r) rmax[mi][r] = fmaxf(rmax[mi][r], acc[r]);
      }
    }
  }
#pragma unroll
  for (int mi = 0; mi < 8; ++mi)
#pragma unroll
    for (int r = 0; r < 4; ++r) {
      float v = rmax[mi][r];
      v = fmaxf(v, __shfl_xor(v, 1)); v = fmaxf(v, __shfl_xor(v, 2));
      v = fmaxf(v, __shfl_xor(v, 4)); v = fmaxf(v, __shfl_xor(v, 8));
      if (lm == 0) redm[mi * 16 + q * 4 + r][w] = v;
    }
  __syncthreads();
  if (t < 128) {
    float m = fmaxf(fmaxf(redm[t][0], redm[t][1]), fmaxf(redm[t][2], redm[t][3]));
    float dot = 0.f;
    const float* kp = ksum + bh * DHn;
#pragma unroll
    for (int d = 0; d < 64; ++d)
      dot += ((float)sQh[t * 64 + d] + (float)sQl[t * 64 + d]) * kp[d];
    row_max[(size_t)bh * Ln + q0 + t] = m * PSC;
    spars[(size_t)bh * Ln + q0 + t] = m * PSC - dot * (PSC / (float)Ln);
  }
}

// ---------------- top-U: bitonic sort on approx spars + EXACT fp32 boundary refine ----------------
__global__ __launch_bounds__(256) void topk_refine(
    const float* __restrict__ spars, const float* __restrict__ Qf,
    const float* __restrict__ Kf, int* __restrict__ top_idx) {
  __shared__ unsigned long long keys[Ln];   // 16 KB
  __shared__ float Qw[16][64];
  __shared__ int wrow[16];
  __shared__ float redm2[16][4], reds2[16][4];
  __shared__ float spx[16];
  const int t = threadIdx.x;
  const int bh = blockIdx.x, b = bh >> 4, h = bh & 15;
  for (int i = t; i < Ln; i += 256) {
    unsigned u = __float_as_uint(spars[(size_t)bh * Ln + i]);
    u = (u & 0x80000000u) ? ~u : (u | 0x80000000u);
    u = ~u;
    keys[i] = ((unsigned long long)u << 32) | (unsigned)i;
  }
  __syncthreads();
  for (unsigned k = 2; k <= Ln; k <<= 1) {
    for (unsigned j = k >> 1; j > 0; j >>= 1) {
#pragma unroll
      for (int p = 0; p < Ln / 256; ++p) {
        int i = p * 256 + t;
        int ixj = i ^ (int)j;
        if (ixj > i) {
          unsigned long long a = keys[i], bb = keys[ixj];
          bool up = ((i & (int)k) == 0);
          if ((a > bb) == up) { keys[i] = bb; keys[ixj] = a; }
        }
      }
      __syncthreads();
    }
  }
  // bulk: ranks [0, U-8) from approx order (safe: boundary margin >> approx error)
  for (int u = t; u < Un - 8; u += 256)
    top_idx[(size_t)bh * Un + u] = (int)(keys[u] & 0xFFFFFFFFu);
  if (t < 16) wrow[t] = (int)(keys[Un - 8 + t] & 0xFFFFFFFFu);  // ranks [U-8, U+8)
  __syncthreads();
  for (int i = t; i < 16 * 64; i += 256) {
    int j = i >> 6, d = i & 63;
    Qw[j][d] = Qf[((size_t)b * Ln + wrow[j]) * Dn + h * DHn + d];
  }
  __syncthreads();
  // exact fp32 scores for the 16 window rows over all 2048 keys (8 keys/thread)
  float rmax[16], rsum[16];
#pragma unroll
  for (int j = 0; j < 16; ++j) { rmax[j] = -1e30f; rsum[j] = 0.f; }
  for (int li = 0; li < 8; ++li) {
    int l = t * 8 + li;
    const float* kp = &Kf[((size_t)b * Ln + l) * Dn + h * DHn];
    float sacc[16];
#pragma unroll
    for (int j = 0; j < 16; ++j) sacc[j] = 0.f;
#pragma unroll
    for (int d0 = 0; d0 < 64; d0 += 16) {
      float kc[16];
      *(float4*)&kc[0]  = *(const float4*)&kp[d0];
      *(float4*)&kc[4]  = *(const float4*)&kp[d0 + 4];
      *(float4*)&kc[8]  = *(const float4*)&kp[d0 + 8];
      *(float4*)&kc[12] = *(const float4*)&kp[d0 + 12];
#pragma unroll
      for (int j = 0; j < 16; ++j)
#pragma unroll
        for (int dd = 0; dd < 16; ++dd)
          sacc[j] = fmaf(kc[dd], Qw[j][d0 + dd], sacc[j]);
    }
#pragma unroll
    for (int j = 0; j < 16; ++j) { rmax[j] = fmaxf(rmax[j], sacc[j]); rsum[j] += sacc[j]; }
  }
  const int w = t >> 6, lane = t & 63;
#pragma unroll
  for (int j = 0; j < 16; ++j) {
    float m = rmax[j], s = rsum[j];
#pragma unroll
    for (int off = 1; off < 64; off <<= 1) {
      m = fmaxf(m, __shfl_xor(m, off));
      s += __shfl_xor(s, off);
    }
    if (lane == 0) { redm2[j][w] = m; reds2[j][w] = s; }
  }
  __syncthreads();
  if (t < 16) {
    float m = fmaxf(fmaxf(redm2[t][0], redm2[t][1]), fmaxf(redm2[t][2], redm2[t][3]));
    double s = (double)reds2[t][0] + (double)reds2[t][1] + (double)reds2[t][2] + (double)reds2[t][3];
    spx[t] = (float)(0.125 * ((double)m - s / 2048.0));
  }
  __syncthreads();
  if (t == 0) {
    unsigned taken = 0;
    for (int r = 0; r < 8; ++r) {
      int best = -1;
      for (int j = 0; j < 16; ++j) {
        if (taken & (1u << j)) continue;
        if (best < 0 || spx[j] > spx[best] ||
            (spx[j] == spx[best] && wrow[j] < wrow[best])) best = j;
      }
      taken |= 1u << best;
      top_idx[(size_t)bh * Un + (Un - 8) + r] = wrow[best];
    }
  }
}

// ---------------- selected-row attention (split-fp16 MFMA), scatter AO' hi/lo ----------------
__global__ __launch_bounds__(256) void attn_sel_mfma(
    const f16* __restrict__ Qh, const f16* __restrict__ Ql,
    const f16* __restrict__ Kh, const f16* __restrict__ Kl,
    const f16* __restrict__ Vth, const f16* __restrict__ Vtl,
    const int* __restrict__ topi, const float* __restrict__ row_max,
    f16* __restrict__ AOh, f16* __restrict__ AOl) {
  __shared__ f16 sQh[64 * 64], sQl[64 * 64];
  __shared__ f16 sKh[64 * 64], sKl[64 * 64];
  __shared__ f16 sVh[64 * 64], sVl[64 * 64];
  __shared__ f16 sPh[64 * 72], sPl[64 * 72];
  __shared__ float rmL[64];
  __shared__ int qxL[64];
  __shared__ float dred[64][5];
  const int t = threadIdx.x;
  const int w = t >> 6, lane = t & 63, lm = lane & 15, q = lane >> 4;
  const int bh = blockIdx.y, b = bh >> 4, h = bh & 15;
  const int u0 = blockIdx.x * 64;
  const int nrows = (Un - u0 < 64) ? (Un - u0) : 64;
  if (t < 64) {
    int qi = topi[(size_t)bh * Un + ((t < nrows) ? (u0 + t) : 0)];
    qxL[t] = qi;
    rmL[t] = row_max[(size_t)bh * Ln + qi];
  }
  __syncthreads();
#pragma unroll
  for (int c = 0; c < 2; ++c) {
    int f = (c * 256 + t) * 8; int row = f >> 6, col = f & 63;
    int qi = qxL[row];
    size_t go = ((size_t)b * Ln + qi) * Dn + h * DHn + col;
    *(uint4*)&sQh[f] = *(const uint4*)&Qh[go];
    *(uint4*)&sQl[f] = *(const uint4*)&Ql[go];
  }
  float rmv[4][4];
#pragma unroll
  for (int mi = 0; mi < 4; ++mi)
#pragma unroll
    for (int r = 0; r < 4; ++r) rmv[mi][r] = rmL[mi * 16 + q * 4 + r];
  f32x4 oacc[4] = {};
  float dacc[4][4] = {};

  for (int kt = 0; kt < Ln / 64; ++kt) {
    const int l0 = kt * 64;
    __syncthreads();
    const f16* kh = Kh + ((size_t)b * Ln + l0) * Dn + h * DHn;
    const f16* kl = Kl + ((size_t)b * Ln + l0) * Dn + h * DHn;
    const f16* vh = Vth + (size_t)bh * DHn * Ln + l0;
    const f16* vl = Vtl + (size_t)bh * DHn * Ln + l0;
#pragma unroll
    for (int c = 0; c < 2; ++c) {
      int f = (c * 256 + t) * 8; int row = f >> 6, col = f & 63;
      gl_lds16(kh + (size_t)row * Dn + col, &sKh[f]);
      gl_lds16(kl + (size_t)row * Dn + col, &sKl[f]);
      gl_lds16(vh + (size_t)row * Ln + col, &sVh[f]);
      gl_lds16(vl + (size_t)row * Ln + col, &sVl[f]);
    }
    __syncthreads();
    f16x8 kb_h[2], kb_l[2];
#pragma unroll
    for (int ks = 0; ks < 2; ++ks) {
      int r = (w * 16 + lm) * 64 + ks * 32 + q * 8;
      kb_h[ks] = *(const f16x8*)&sKh[r];
      kb_l[ks] = *(const f16x8*)&sKl[r];
    }
#pragma unroll
    for (int mi = 0; mi < 4; ++mi) {
      f32x4 acc = {0.f, 0.f, 0.f, 0.f};
#pragma unroll
      for (int ks = 0; ks < 2; ++ks) {
        int r = (mi * 16 + lm) * 64 + ks * 32 + q * 8;
        f16x8 a_h = *(const f16x8*)&sQh[r];
        f16x8 a_l = *(const f16x8*)&sQl[r];
        acc = MFMA(a_h, kb_h[ks], acc);
        acc = MFMA(a_h, kb_l[ks], acc);
        acc = MFMA(a_l, kb_h[ks], acc);
      }
#pragma unroll
      for (int r = 0; r < 4; ++r) {
        float p = __expf(acc[r] * PSC - rmv[mi][r]);   // rm = true max -> p <= ~1
        dacc[mi][r] += p;
        f16 ph, pl; splitf16(p * SPf, ph, pl);
        int row = mi * 16 + q * 4 + r, col = w * 16 + lm;
        sPh[row * 72 + col] = ph;
        sPl[row * 72 + col] = pl;
      }
    }
    __syncthreads();
    f16x8 vb_h[2], vb_l[2];
#pragma unroll
    for (int ks = 0; ks < 2; ++ks) {
      int r = (w * 16 + lm) * 64 + ks * 32 + q * 8;
      vb_h[ks] = *(const f16x8*)&sVh[r];
      vb_l[ks] = *(const f16x8*)&sVl[r];
    }
#pragma unroll
    for (int mi = 0; mi < 4; ++mi) {
#pragma unroll
      for (int ks = 0; ks < 2; ++ks) {
        int r = (mi * 16 + lm) * 72 + ks * 32 + q * 8;
        f16x8 p_h = *(const f16x8*)&sPh[r];
        f16x8 p_l = *(const f16x8*)&sPl[r];
        oacc[mi] = MFMA(p_h, vb_h[ks], oacc[mi]);
        oacc[mi] = MFMA(p_h, vb_l[ks], oacc[mi]);
        oacc[mi] = MFMA(p_l, vb_h[ks], oacc[mi]);
      }
    }
  }
#pragma unroll
  for (int mi = 0; mi < 4; ++mi)
#pragma unroll
    for (int r = 0; r < 4; ++r) {
      float v = dacc[mi][r];
      v += __shfl_xor(v, 1); v += __shfl_xor(v, 2);
      v += __shfl_xor(v, 4); v += __shfl_xor(v, 8);
      if (lm == 0) dred[mi * 16 + q * 4 + r][w] = v;
    }
  __syncthreads();
#pragma unroll
  for (int mi = 0; mi < 4; ++mi)
#pragma unroll
    for (int r = 0; r < 4; ++r) {
      int row = mi * 16 + q * 4 + r;
      if (row < nrows) {
        // oacc = SP*SV * sum(p v); AO' = SA*AO = oacc/dsum  (SP*SV == SA/1 scaling folds out)
        float dinv = 1.0f / (dred[row][0] + dred[row][1] + dred[row][2] + dred[row][3]);
        int qi = qxL[row];
        f16 hh, ll; splitf16(oacc[mi][r] * dinv, hh, ll);
        size_t o = ((size_t)b * Ln + qi) * Dn + h * DHn + w * 16 + lm;
        AOh[o] = hh; AOl[o] = ll;
      }
    }
}

extern "C" void kernel_launch(void* const* d_in, const int* in_sizes, int n_in,
                              void* d_out, int out_size, void* d_ws, size_t ws_size,
                              hipStream_t stream) {
  (void)in_sizes; (void)n_in; (void)out_size; (void)ws_size;
  const float* x  = (const float*)d_in[0];
  const float* Wq = (const float*)d_in[1];
  const float* bq = (const float*)d_in[2];
  const float* Wk = (const float*)d_in[3];
  const float* bk = (const float*)d_in[4];
  const float* Wv = (const float*)d_in[5];
  const float* bv = (const float*)d_in[6];
  const float* Wo = (const float*)d_in[7];
  const float* bo = (const float*)d_in[8];
  float* out = (float*)d_out;

  uint8_t* p = (uint8_t*)d_ws;
  const size_t NE = (size_t)Bn * Ln * Dn;          // 4 Mi elements
  f16* xh = (f16*)p;  p += NE * 2;
  f16* xl = (f16*)p;  p += NE * 2;
  f16* Wt_h[4]; f16* Wt_l[4];
  for (int i = 0; i < 4; ++i) {
    Wt_h[i] = (f16*)p; p += (size_t)Dn * Dn * 2;
    Wt_l[i] = (f16*)p; p += (size_t)Dn * Dn * 2;
  }
  f16* Qbh = (f16*)p; p += NE * 2;
  f16* Qbl = (f16*)p; p += NE * 2;
  f16* Kbh = (f16*)p; p += NE * 2;
  f16* Kbl = (f16*)p; p += NE * 2;
  float* Qf = (float*)p;  p += NE * 4;
  float* Kf = (float*)p;  p += NE * 4;
  float* Vf = (float*)p;  p += NE * 4;
  f16* Vth = (f16*)p; p += NE * 2;
  f16* Vtl = (f16*)p; p += NE * 2;
  float* rowmax = (float*)p; p += (size_t)BHn * Ln * 4;
  float* spars  = (float*)p; p += (size_t)BHn * Ln * 4;
  float* ksum   = (float*)p; p += (size_t)BHn * DHn * 4;
  int* topi     = (int*)p;   p += (size_t)BHn * Un * 4;
  f16* AOh = xh;   // alias: x split dead after V-GEMM
  f16* AOl = xl;

  dim3 blk(256);
  hipLaunchKernelGGL(split_kernel, dim3((int)(NE / 4 / 256)), blk, 0, stream, x, xh, xl, (int)(NE / 4));
  hipLaunchKernelGGL(tsplit_w, dim3(16, 16), blk, 0, stream, Wq, Wt_h[0], Wt_l[0]);
  hipLaunchKernelGGL(tsplit_w, dim3(16, 16), blk, 0, stream, Wk, Wt_h[1], Wt_l[1]);
  hipLaunchKernelGGL(tsplit_w, dim3(16, 16), blk, 0, stream, Wv, Wt_h[2], Wt_l[2]);
  hipLaunchKernelGGL(tsplit_w, dim3(16, 16), blk, 0, stream, Wo, Wt_h[3], Wt_l[3]);

  dim3 gg(Dn / 128, (Bn * Ln) / 128);
  hipLaunchKernelGGL(gemm_split, gg, blk, 0, stream, xh, xl, Wt_h[0], Wt_l[0], bq,
                     ESC_PROJ, SQf, Qf, Qbh, Qbl, Bn * Ln, Dn, Dn);
  hipLaunchKernelGGL(gemm_split, gg, blk, 0, stream, xh, xl, Wt_h[1], Wt_l[1], bk,
                     ESC_PROJ, SQf, Kf, Kbh, Kbl, Bn * Ln, Dn, Dn);
  hipLaunchKernelGGL(gemm_split, gg, blk, 0, stream, xh, xl, Wt_h[2], Wt_l[2], bv,
                     ESC_PROJ, 1.0f, Vf, (f16*)nullptr, (f16*)nullptr, Bn * Ln, Dn, Dn);
  hipLaunchKernelGGL(tsplit_v, dim3(Ln / 64, BHn), blk, 0, stream, Vf, Vth, Vtl);
  hipLaunchKernelGGL(ksum_kernel, dim3(BHn), blk, 0, stream, Kbh, Kbl, ksum);
  hipLaunchKernelGGL(attn_stats_mfma, dim3(Ln / 128, BHn), blk, 0, stream,
                     Qbh, Qbl, Kbh, Kbl, ksum, rowmax, spars);
  hipLaunchKernelGGL(topk_refine, dim3(BHn), blk, 0, stream, spars, Qf, Kf, topi);
  hipMemsetAsync(AOh, 0, NE * 2, stream);
  hipMemsetAsync(AOl, 0, NE * 2, stream);
  hipLaunchKernelGGL(attn_sel_mfma, dim3((Un + 63) / 64, BHn), blk, 0, stream,
                     Qbh, Qbl, Kbh, Kbl, Vth, Vtl, topi, rowmax, AOh, AOl);
  hipLaunchKernelGGL(gemm_split, gg, blk, 0, stream, AOh, AOl, Wt_h[3], Wt_l[3], bo,
                     ESC_OUT, 1.0f, out, (f16*)nullptr, (f16*)nullptr, Bn * Ln, Dn, Dn);
}

// Round 4
// 651.684 us; speedup vs baseline: 2.4201x; 1.4678x over previous
//
#include <hip/hip_runtime.h>
#include <math.h>
#include <stdint.h>

#define Bn 2
#define Ln 2048
#define Dn 1024
#define Hn 16
#define DHn 64
#define Un 1228
#define BHn (Bn*Hn)
#define SCALE 0.125f
// pre-split power-of-2 scales (dodge fp16 subnormal flush on lo terms)
#define SXf 16.0f     // x
#define SWf 256.0f    // all W
#define SQf 16.0f     // Q, K
#define SVf 16.0f     // V
#define SPf 16.0f     // softmax P
#define ESC_PROJ (1.0f / 4096.0f)    // 1/(SX*SW)
#define ESC_OUT  (1.0f / 65536.0f)   // 1/(SA*SW)
#define PSC (SCALE / 256.0f)         // score unscale: 1/(SQ*SQ) * SCALE

typedef _Float16 f16;
typedef __attribute__((ext_vector_type(8))) _Float16 f16x8;
typedef __attribute__((ext_vector_type(4))) float f32x4;
struct h4s { f16 x, y, z, w; };

__device__ __forceinline__ void splitf16(float f, f16& hi, f16& lo) {
  hi = (f16)f;                 // RTNE
  lo = (f16)(f - (float)hi);   // residual, ~22 mantissa bits total
}

// async global->LDS, 16B per lane (wave-uniform base + lane*16)
__device__ __forceinline__ void gl_lds16(const void* g, void* l) {
  __builtin_amdgcn_global_load_lds(
      (const __attribute__((address_space(1))) void*)g,
      (__attribute__((address_space(3))) void*)l, 16, 0, 0);
}

#define MFMA(a, b, c) __builtin_amdgcn_mfma_f32_16x16x32_f16((a), (b), (c), 0, 0, 0)

// ---------------- split x*16 -> xh, xl ----------------
__global__ __launch_bounds__(256) void split_kernel(
    const float* __restrict__ in, f16* __restrict__ oh, f16* __restrict__ ol, int n4) {
  int i = blockIdx.x * 256 + threadIdx.x;
  if (i >= n4) return;
  float4 v = ((const float4*)in)[i];
  h4s h, l;
  splitf16(v.x * SXf, h.x, l.x); splitf16(v.y * SXf, h.y, l.y);
  splitf16(v.z * SXf, h.z, l.z); splitf16(v.w * SXf, h.w, l.w);
  ((h4s*)oh)[i] = h; ((h4s*)ol)[i] = l;
}

// ---------------- transpose + split W*256: W[k][n] -> Wt[n][k] hi/lo ----------------
__global__ __launch_bounds__(256) void tsplit_w(
    const float* __restrict__ in, f16* __restrict__ oh, f16* __restrict__ ol) {
  __shared__ float ts[64][65];
  const int t = threadIdx.x;
  const int r0 = blockIdx.x * 64, c0 = blockIdx.y * 64;
#pragma unroll
  for (int c = 0; c < 4; ++c) {
    int f = (c * 256 + t) * 4; int row = f >> 6, col = f & 63;
    float4 v = *(const float4*)&in[(size_t)(r0 + row) * Dn + c0 + col];
    ts[row][col] = v.x; ts[row][col + 1] = v.y; ts[row][col + 2] = v.z; ts[row][col + 3] = v.w;
  }
  __syncthreads();
#pragma unroll
  for (int c = 0; c < 4; ++c) {
    int f = (c * 256 + t) * 4; int crow = f >> 6, rcol = f & 63;
    h4s h, l;
    splitf16(ts[rcol + 0][crow] * SWf, h.x, l.x);
    splitf16(ts[rcol + 1][crow] * SWf, h.y, l.y);
    splitf16(ts[rcol + 2][crow] * SWf, h.z, l.z);
    splitf16(ts[rcol + 3][crow] * SWf, h.w, l.w);
    size_t o = (size_t)(c0 + crow) * Dn + r0 + rcol;
    *(h4s*)&oh[o] = h; *(h4s*)&ol[o] = l;
  }
}

// ---------------- transpose + split V*16: V[b,l,D] -> Vt[bh*64+d][L] hi/lo ----------------
__global__ __launch_bounds__(256) void tsplit_v(
    const float* __restrict__ Vf, f16* __restrict__ oh, f16* __restrict__ ol) {
  __shared__ float ts[64][65];
  const int t = threadIdx.x;
  const int l0 = blockIdx.x * 64;
  const int bh = blockIdx.y, b = bh >> 4, h = bh & 15;
#pragma unroll
  for (int c = 0; c < 4; ++c) {
    int f = (c * 256 + t) * 4; int lrow = f >> 6, dcol = f & 63;
    float4 v = *(const float4*)&Vf[((size_t)b * Ln + l0 + lrow) * Dn + h * DHn + dcol];
    ts[lrow][dcol] = v.x; ts[lrow][dcol + 1] = v.y; ts[lrow][dcol + 2] = v.z; ts[lrow][dcol + 3] = v.w;
  }
  __syncthreads();
#pragma unroll
  for (int c = 0; c < 4; ++c) {
    int f = (c * 256 + t) * 4; int drow = f >> 6, lcol = f & 63;
    h4s h4, l4;
    splitf16(ts[lcol + 0][drow] * SVf, h4.x, l4.x);
    splitf16(ts[lcol + 1][drow] * SVf, h4.y, l4.y);
    splitf16(ts[lcol + 2][drow] * SVf, h4.z, l4.z);
    splitf16(ts[lcol + 3][drow] * SVf, h4.w, l4.w);
    size_t o = ((size_t)bh * DHn + drow) * Ln + l0 + lcol;
    *(h4s*)&oh[o] = h4; *(h4s*)&ol[o] = l4;
  }
}

// ---------------- split-fp16 MFMA GEMM: C = (A @ Bt^T)*escale + bias ----------------
__global__ __launch_bounds__(256) void gemm_split(
    const f16* __restrict__ Ah, const f16* __restrict__ Al,
    const f16* __restrict__ Bth, const f16* __restrict__ Btl,
    const float* __restrict__ bias, float escale, float osplit,
    float* __restrict__ Cf, f16* __restrict__ Ch, f16* __restrict__ Cl,
    int M, int N, int K) {
  __shared__ f16 sAh[128 * 32], sAl[128 * 32], sBh[128 * 32], sBl[128 * 32];
  const int t = threadIdx.x;
  const int w = t >> 6, lane = t & 63, lm = lane & 15, q = lane >> 4;
  const int wr = w >> 1, wc = w & 1;
  const int n0 = blockIdx.x * 128, m0 = blockIdx.y * 128;
  f32x4 acc[4][4] = {};
  for (int k0 = 0; k0 < K; k0 += 32) {
    const f16* s0 = Ah + (size_t)m0 * K + k0;
    const f16* s1 = Al + (size_t)m0 * K + k0;
    const f16* s2 = Bth + (size_t)n0 * K + k0;
    const f16* s3 = Btl + (size_t)n0 * K + k0;
#pragma unroll
    for (int c = 0; c < 2; ++c) {
      int f = (c * 256 + t) * 8; int row = f >> 5, col = f & 31;
      size_t go = (size_t)row * K + col;
      gl_lds16(s0 + go, &sAh[f]);
      gl_lds16(s1 + go, &sAl[f]);
      gl_lds16(s2 + go, &sBh[f]);
      gl_lds16(s3 + go, &sBl[f]);
    }
    __syncthreads();
    f16x8 a_h[4], a_l[4], b_h[4], b_l[4];
#pragma unroll
    for (int mi = 0; mi < 4; ++mi) {
      int r = (wr * 64 + mi * 16 + lm) * 32 + q * 8;
      a_h[mi] = *(const f16x8*)&sAh[r];
      a_l[mi] = *(const f16x8*)&sAl[r];
    }
#pragma unroll
    for (int ni = 0; ni < 4; ++ni) {
      int r = (wc * 64 + ni * 16 + lm) * 32 + q * 8;
      b_h[ni] = *(const f16x8*)&sBh[r];
      b_l[ni] = *(const f16x8*)&sBl[r];
    }
#pragma unroll
    for (int mi = 0; mi < 4; ++mi)
#pragma unroll
      for (int ni = 0; ni < 4; ++ni) {
        acc[mi][ni] = MFMA(a_h[mi], b_h[ni], acc[mi][ni]);
        acc[mi][ni] = MFMA(a_h[mi], b_l[ni], acc[mi][ni]);
        acc[mi][ni] = MFMA(a_l[mi], b_h[ni], acc[mi][ni]);
      }
    __syncthreads();
  }
#pragma unroll
  for (int mi = 0; mi < 4; ++mi)
#pragma unroll
    for (int ni = 0; ni < 4; ++ni) {
      int gcol = n0 + wc * 64 + ni * 16 + lm;
      float bv = bias[gcol];
#pragma unroll
      for (int r = 0; r < 4; ++r) {
        int grow = m0 + wr * 64 + mi * 16 + q * 4 + r;
        float v = acc[mi][ni][r] * escale + bv;
        size_t o = (size_t)grow * N + gcol;
        if (Cf) Cf[o] = v;
        if (Ch) { f16 hh, ll; splitf16(v * osplit, hh, ll); Ch[o] = hh; Cl[o] = ll; }
      }
    }
}

// ---------------- ksum[bh][d] = sum_l K'[b,l,h*64+d] ----------------
__global__ __launch_bounds__(256) void ksum_kernel(
    const f16* __restrict__ Kh, const f16* __restrict__ Kl, float* __restrict__ ksum) {
  __shared__ float red[4][64];
  const int t = threadIdx.x, d = t & 63, seg = t >> 6;
  const int bh = blockIdx.x, b = bh >> 4, h = bh & 15;
  float s = 0.f;
  for (int l = seg * 512; l < (seg + 1) * 512; ++l) {
    size_t o = ((size_t)b * Ln + l) * Dn + h * DHn + d;
    s += (float)Kh[o] + (float)Kl[o];
  }
  red[seg][d] = s;
  __syncthreads();
  if (t < 64) ksum[bh * DHn + t] = red[0][t] + red[1][t] + red[2][t] + red[3][t];
}

// ---------------- stats: approx row max (MFMA) + spars = max - mean ----------------
__global__ __launch_bounds__(256) void attn_stats_mfma(
    const f16* __restrict__ Qh, const f16* __restrict__ Ql,
    const f16* __restrict__ Kh, const f16* __restrict__ Kl,
    const float* __restrict__ ksum,
    float* __restrict__ row_max, float* __restrict__ spars) {
  __shared__ f16 sQh[128 * 64], sQl[128 * 64], sKh[128 * 64], sKl[128 * 64];
  __shared__ float redm[128][5];
  const int t = threadIdx.x;
  const int w = t >> 6, lane = t & 63, lm = lane & 15, q = lane >> 4;
  const int bh = blockIdx.y, b = bh >> 4, h = bh & 15;
  const int q0 = blockIdx.x * 128;
  const f16* qsh = Qh + ((size_t)b * Ln + q0) * Dn + h * DHn;
  const f16* qsl = Ql + ((size_t)b * Ln + q0) * Dn + h * DHn;
#pragma unroll
  for (int c = 0; c < 4; ++c) {
    int f = (c * 256 + t) * 8; int row = f >> 6, col = f & 63;
    size_t go = (size_t)row * Dn + col;
    gl_lds16(qsh + go, &sQh[f]);
    gl_lds16(qsl + go, &sQl[f]);
  }
  float rmax[8][4];
#pragma unroll
  for (int mi = 0; mi < 8; ++mi)
#pragma unroll
    for (int r = 0; r < 4; ++r) rmax[mi][r] = -1e30f;

  for (int kt = 0; kt < Ln / 128; ++kt) {
    __syncthreads();
    const f16* ksh = Kh + ((size_t)b * Ln + kt * 128) * Dn + h * DHn;
    const f16* ksl = Kl + ((size_t)b * Ln + kt * 128) * Dn + h * DHn;
#pragma unroll
    for (int c = 0; c < 4; ++c) {
      int f = (c * 256 + t) * 8; int row = f >> 6, col = f & 63;
      size_t go = (size_t)row * Dn + col;
      gl_lds16(ksh + go, &sKh[f]);
      gl_lds16(ksl + go, &sKl[f]);
    }
    __syncthreads();
#pragma unroll
    for (int ni = 0; ni < 2; ++ni) {
      int bcol = (w * 2 + ni) * 16;
      f16x8 b_h[2], b_l[2];
#pragma unroll
      for (int ks = 0; ks < 2; ++ks) {
        int r = (bcol + lm) * 64 + ks * 32 + q * 8;
        b_h[ks] = *(const f16x8*)&sKh[r];
        b_l[ks] = *(const f16x8*)&sKl[r];
      }
#pragma unroll
      for (int mi = 0; mi < 8; ++mi) {
        f32x4 acc = {0.f, 0.f, 0.f, 0.f};
#pragma unroll
        for (int ks = 0; ks < 2; ++ks) {
          int r = (mi * 16 + lm) * 64 + ks * 32 + q * 8;
          f16x8 a_h = *(const f16x8*)&sQh[r];
          f16x8 a_l = *(const f16x8*)&sQl[r];
          acc = MFMA(a_h, b_h[ks], acc);
          acc = MFMA(a_h, b_l[ks], acc);
          acc = MFMA(a_l, b_h[ks], acc);
        }
#pragma unroll
        for (int r = 0; r < 4; ++r) rmax[mi][r] = fmaxf(rmax[mi][r], acc[r]);
      }
    }
  }
#pragma unroll
  for (int mi = 0; mi < 8; ++mi)
#pragma unroll
    for (int r = 0; r < 4; ++r) {
      float v = rmax[mi][r];
      v = fmaxf(v, __shfl_xor(v, 1)); v = fmaxf(v, __shfl_xor(v, 2));
      v = fmaxf(v, __shfl_xor(v, 4)); v = fmaxf(v, __shfl_xor(v, 8));
      if (lm == 0) redm[mi * 16 + q * 4 + r][w] = v;
    }
  __syncthreads();
  if (t < 128) {
    float m = fmaxf(fmaxf(redm[t][0], redm[t][1]), fmaxf(redm[t][2], redm[t][3]));
    float dot = 0.f;
    const float* kp = ksum + bh * DHn;
#pragma unroll
    for (int d = 0; d < 64; ++d)
      dot += ((float)sQh[t * 64 + d] + (float)sQl[t * 64 + d]) * kp[d];
    row_max[(size_t)bh * Ln + q0 + t] = m * PSC;
    spars[(size_t)bh * Ln + q0 + t] = m * PSC - dot * (PSC / (float)Ln);
  }
}

// ---------------- bitonic sort on approx spars; bulk top + 16-row boundary window ----------------
__global__ __launch_bounds__(256) void topk_sort(
    const float* __restrict__ spars, int* __restrict__ top_idx, int* __restrict__ wrow) {
  __shared__ unsigned long long keys[Ln];   // 16 KB
  const int t = threadIdx.x;
  const int bh = blockIdx.x;
  for (int i = t; i < Ln; i += 256) {
    unsigned u = __float_as_uint(spars[(size_t)bh * Ln + i]);
    u = (u & 0x80000000u) ? ~u : (u | 0x80000000u);
    u = ~u;
    keys[i] = ((unsigned long long)u << 32) | (unsigned)i;
  }
  __syncthreads();
  for (unsigned k = 2; k <= Ln; k <<= 1) {
    for (unsigned j = k >> 1; j > 0; j >>= 1) {
#pragma unroll
      for (int p = 0; p < Ln / 256; ++p) {
        int i = p * 256 + t;
        int ixj = i ^ (int)j;
        if (ixj > i) {
          unsigned long long a = keys[i], bb = keys[ixj];
          bool up = ((i & (int)k) == 0);
          if ((a > bb) == up) { keys[i] = bb; keys[ixj] = a; }
        }
      }
      __syncthreads();
    }
  }
  // bulk: ranks [0, U-8) safe from approx order; window ranks [U-8, U+8) refined exactly
  for (int u = t; u < Un - 8; u += 256)
    top_idx[(size_t)bh * Un + u] = (int)(keys[u] & 0xFFFFFFFFu);
  if (t < 16) wrow[bh * 16 + t] = (int)(keys[Un - 8 + t] & 0xFFFFFFFFu);
}

// ---------------- exact fp32 sparsity for one window row per block ----------------
// grid (16, BH). Low register footprint: 1 q-row in LDS, 8 keys/thread.
__global__ __launch_bounds__(256) void refine_rows(
    const float* __restrict__ Qf, const float* __restrict__ Kf,
    const int* __restrict__ wrow, float* __restrict__ spx) {
  __shared__ float qs[64];
  __shared__ float redm[4], reds[4];
  const int t = threadIdx.x;
  const int j = blockIdx.x, bh = blockIdx.y, b = bh >> 4, h = bh & 15;
  const int qi = wrow[bh * 16 + j];
  if (t < 64) qs[t] = Qf[((size_t)b * Ln + qi) * Dn + h * DHn + t];
  __syncthreads();
  float mx = -1e30f, sm = 0.f;
  for (int ki = t; ki < Ln; ki += 256) {
    const float* kp = &Kf[((size_t)b * Ln + ki) * Dn + h * DHn];
    float s = 0.f;
#pragma unroll
    for (int d0 = 0; d0 < 64; d0 += 4) {
      float4 k4 = *(const float4*)&kp[d0];
      s = fmaf(k4.x, qs[d0], s);
      s = fmaf(k4.y, qs[d0 + 1], s);
      s = fmaf(k4.z, qs[d0 + 2], s);
      s = fmaf(k4.w, qs[d0 + 3], s);
    }
    mx = fmaxf(mx, s); sm += s;
  }
  const int w = t >> 6, lane = t & 63;
#pragma unroll
  for (int off = 1; off < 64; off <<= 1) {
    mx = fmaxf(mx, __shfl_xor(mx, off));
    sm += __shfl_xor(sm, off);
  }
  if (lane == 0) { redm[w] = mx; reds[w] = sm; }
  __syncthreads();
  if (t == 0) {
    float m = fmaxf(fmaxf(redm[0], redm[1]), fmaxf(redm[2], redm[3]));
    float s = reds[0] + reds[1] + reds[2] + reds[3];
    spx[bh * 16 + j] = SCALE * (m - s * (1.0f / (float)Ln));
  }
}

// ---------------- pick top-8 of the 16 window rows (exact values) ----------------
__global__ __launch_bounds__(64) void topk_final(
    const float* __restrict__ spx, const int* __restrict__ wrow,
    int* __restrict__ top_idx) {
  const int bh = blockIdx.x;
  if (threadIdx.x != 0) return;
  float v[16]; int r[16];
#pragma unroll
  for (int j = 0; j < 16; ++j) { v[j] = spx[bh * 16 + j]; r[j] = wrow[bh * 16 + j]; }
  unsigned taken = 0;
  for (int s = 0; s < 8; ++s) {
    int best = -1;
    for (int j = 0; j < 16; ++j) {
      if (taken & (1u << j)) continue;
      if (best < 0 || v[j] > v[best] || (v[j] == v[best] && r[j] < r[best])) best = j;
    }
    taken |= 1u << best;
    top_idx[(size_t)bh * Un + (Un - 8) + s] = r[best];
  }
}

// ---------------- selected-row attention (split-fp16 MFMA), scatter AO' hi/lo ----------------
__global__ __launch_bounds__(256) void attn_sel_mfma(
    const f16* __restrict__ Qh, const f16* __restrict__ Ql,
    const f16* __restrict__ Kh, const f16* __restrict__ Kl,
    const f16* __restrict__ Vth, const f16* __restrict__ Vtl,
    const int* __restrict__ topi, const float* __restrict__ row_max,
    f16* __restrict__ AOh, f16* __restrict__ AOl) {
  __shared__ f16 sQh[64 * 64], sQl[64 * 64];
  __shared__ f16 sKh[64 * 64], sKl[64 * 64];
  __shared__ f16 sVh[64 * 64], sVl[64 * 64];
  __shared__ f16 sPh[64 * 72], sPl[64 * 72];
  __shared__ float rmL[64];
  __shared__ int qxL[64];
  __shared__ float dred[64][5];
  const int t = threadIdx.x;
  const int w = t >> 6, lane = t & 63, lm = lane & 15, q = lane >> 4;
  const int bh = blockIdx.y, b = bh >> 4, h = bh & 15;
  const int u0 = blockIdx.x * 64;
  const int nrows = (Un - u0 < 64) ? (Un - u0) : 64;
  if (t < 64) {
    int qi = topi[(size_t)bh * Un + ((t < nrows) ? (u0 + t) : 0)];
    qxL[t] = qi;
    rmL[t] = row_max[(size_t)bh * Ln + qi];
  }
  __syncthreads();
#pragma unroll
  for (int c = 0; c < 2; ++c) {
    int f = (c * 256 + t) * 8; int row = f >> 6, col = f & 63;
    int qi = qxL[row];
    size_t go = ((size_t)b * Ln + qi) * Dn + h * DHn + col;
    *(uint4*)&sQh[f] = *(const uint4*)&Qh[go];
    *(uint4*)&sQl[f] = *(const uint4*)&Ql[go];
  }
  float rmv[4][4];
#pragma unroll
  for (int mi = 0; mi < 4; ++mi)
#pragma unroll
    for (int r = 0; r < 4; ++r) rmv[mi][r] = rmL[mi * 16 + q * 4 + r];
  f32x4 oacc[4] = {};
  float dacc[4][4] = {};

  for (int kt = 0; kt < Ln / 64; ++kt) {
    const int l0 = kt * 64;
    __syncthreads();
    const f16* kh = Kh + ((size_t)b * Ln + l0) * Dn + h * DHn;
    const f16* kl = Kl + ((size_t)b * Ln + l0) * Dn + h * DHn;
    const f16* vh = Vth + (size_t)bh * DHn * Ln + l0;
    const f16* vl = Vtl + (size_t)bh * DHn * Ln + l0;
#pragma unroll
    for (int c = 0; c < 2; ++c) {
      int f = (c * 256 + t) * 8; int row = f >> 6, col = f & 63;
      gl_lds16(kh + (size_t)row * Dn + col, &sKh[f]);
      gl_lds16(kl + (size_t)row * Dn + col, &sKl[f]);
      gl_lds16(vh + (size_t)row * Ln + col, &sVh[f]);
      gl_lds16(vl + (size_t)row * Ln + col, &sVl[f]);
    }
    __syncthreads();
    f16x8 kb_h[2], kb_l[2];
#pragma unroll
    for (int ks = 0; ks < 2; ++ks) {
      int r = (w * 16 + lm) * 64 + ks * 32 + q * 8;
      kb_h[ks] = *(const f16x8*)&sKh[r];
      kb_l[ks] = *(const f16x8*)&sKl[r];
    }
#pragma unroll
    for (int mi = 0; mi < 4; ++mi) {
      f32x4 acc = {0.f, 0.f, 0.f, 0.f};
#pragma unroll
      for (int ks = 0; ks < 2; ++ks) {
        int r = (mi * 16 + lm) * 64 + ks * 32 + q * 8;
        f16x8 a_h = *(const f16x8*)&sQh[r];
        f16x8 a_l = *(const f16x8*)&sQl[r];
        acc = MFMA(a_h, kb_h[ks], acc);
        acc = MFMA(a_h, kb_l[ks], acc);
        acc = MFMA(a_l, kb_h[ks], acc);
      }
#pragma unroll
      for (int r = 0; r < 4; ++r) {
        float p = __expf(acc[r] * PSC - rmv[mi][r]);   // rm = true max -> p <= ~1
        dacc[mi][r] += p;
        f16 ph, pl; splitf16(p * SPf, ph, pl);
        int row = mi * 16 + q * 4 + r, col = w * 16 + lm;
        sPh[row * 72 + col] = ph;
        sPl[row * 72 + col] = pl;
      }
    }
    __syncthreads();
    f16x8 vb_h[2], vb_l[2];
#pragma unroll
    for (int ks = 0; ks < 2; ++ks) {
      int r = (w * 16 + lm) * 64 + ks * 32 + q * 8;
      vb_h[ks] = *(const f16x8*)&sVh[r];
      vb_l[ks] = *(const f16x8*)&sVl[r];
    }
#pragma unroll
    for (int mi = 0; mi < 4; ++mi) {
#pragma unroll
      for (int ks = 0; ks < 2; ++ks) {
        int r = (mi * 16 + lm) * 72 + ks * 32 + q * 8;
        f16x8 p_h = *(const f16x8*)&sPh[r];
        f16x8 p_l = *(const f16x8*)&sPl[r];
        oacc[mi] = MFMA(p_h, vb_h[ks], oacc[mi]);
        oacc[mi] = MFMA(p_h, vb_l[ks], oacc[mi]);
        oacc[mi] = MFMA(p_l, vb_h[ks], oacc[mi]);
      }
    }
  }
#pragma unroll
  for (int mi = 0; mi < 4; ++mi)
#pragma unroll
    for (int r = 0; r < 4; ++r) {
      float v = dacc[mi][r];
      v += __shfl_xor(v, 1); v += __shfl_xor(v, 2);
      v += __shfl_xor(v, 4); v += __shfl_xor(v, 8);
      if (lm == 0) dred[mi * 16 + q * 4 + r][w] = v;
    }
  __syncthreads();
#pragma unroll
  for (int mi = 0; mi < 4; ++mi)
#pragma unroll
    for (int r = 0; r < 4; ++r) {
      int row = mi * 16 + q * 4 + r;
      if (row < nrows) {
        float dinv = 1.0f / (dred[row][0] + dred[row][1] + dred[row][2] + dred[row][3]);
        int qi = qxL[row];
        f16 hh, ll; splitf16(oacc[mi][r] * dinv, hh, ll);
        size_t o = ((size_t)b * Ln + qi) * Dn + h * DHn + w * 16 + lm;
        AOh[o] = hh; AOl[o] = ll;
      }
    }
}

extern "C" void kernel_launch(void* const* d_in, const int* in_sizes, int n_in,
                              void* d_out, int out_size, void* d_ws, size_t ws_size,
                              hipStream_t stream) {
  (void)in_sizes; (void)n_in; (void)out_size; (void)ws_size;
  const float* x  = (const float*)d_in[0];
  const float* Wq = (const float*)d_in[1];
  const float* bq = (const float*)d_in[2];
  const float* Wk = (const float*)d_in[3];
  const float* bk = (const float*)d_in[4];
  const float* Wv = (const float*)d_in[5];
  const float* bv = (const float*)d_in[6];
  const float* Wo = (const float*)d_in[7];
  const float* bo = (const float*)d_in[8];
  float* out = (float*)d_out;

  uint8_t* p = (uint8_t*)d_ws;
  const size_t NE = (size_t)Bn * Ln * Dn;          // 4 Mi elements
  f16* xh = (f16*)p;  p += NE * 2;
  f16* xl = (f16*)p;  p += NE * 2;
  f16* Wt_h[4]; f16* Wt_l[4];
  for (int i = 0; i < 4; ++i) {
    Wt_h[i] = (f16*)p; p += (size_t)Dn * Dn * 2;
    Wt_l[i] = (f16*)p; p += (size_t)Dn * Dn * 2;
  }
  f16* Qbh = (f16*)p; p += NE * 2;
  f16* Qbl = (f16*)p; p += NE * 2;
  f16* Kbh = (f16*)p; p += NE * 2;
  f16* Kbl = (f16*)p; p += NE * 2;
  float* Qf = (float*)p;  p += NE * 4;
  float* Kf = (float*)p;  p += NE * 4;
  float* Vf = (float*)p;  p += NE * 4;
  f16* Vth = (f16*)p; p += NE * 2;
  f16* Vtl = (f16*)p; p += NE * 2;
  float* rowmax = (float*)p; p += (size_t)BHn * Ln * 4;
  float* spars  = (float*)p; p += (size_t)BHn * Ln * 4;
  float* ksum   = (float*)p; p += (size_t)BHn * DHn * 4;
  int* topi     = (int*)p;   p += (size_t)BHn * Un * 4;
  int* wrow     = (int*)p;   p += (size_t)BHn * 16 * 4;
  float* spx    = (float*)p; p += (size_t)BHn * 16 * 4;
  f16* AOh = xh;   // alias: x split dead after V-GEMM
  f16* AOl = xl;

  dim3 blk(256);
  hipLaunchKernelGGL(split_kernel, dim3((int)(NE / 4 / 256)), blk, 0, stream, x, xh, xl, (int)(NE / 4));
  hipLaunchKernelGGL(tsplit_w, dim3(16, 16), blk, 0, stream, Wq, Wt_h[0], Wt_l[0]);
  hipLaunchKernelGGL(tsplit_w, dim3(16, 16), blk, 0, stream, Wk, Wt_h[1], Wt_l[1]);
  hipLaunchKernelGGL(tsplit_w, dim3(16, 16), blk, 0, stream, Wv, Wt_h[2], Wt_l[2]);
  hipLaunchKernelGGL(tsplit_w, dim3(16, 16), blk, 0, stream, Wo, Wt_h[3], Wt_l[3]);

  dim3 gg(Dn / 128, (Bn * Ln) / 128);
  hipLaunchKernelGGL(gemm_split, gg, blk, 0, stream, xh, xl, Wt_h[0], Wt_l[0], bq,
                     ESC_PROJ, SQf, Qf, Qbh, Qbl, Bn * Ln, Dn, Dn);
  hipLaunchKernelGGL(gemm_split, gg, blk, 0, stream, xh, xl, Wt_h[1], Wt_l[1], bk,
                     ESC_PROJ, SQf, Kf, Kbh, Kbl, Bn * Ln, Dn, Dn);
  hipLaunchKernelGGL(gemm_split, gg, blk, 0, stream, xh, xl, Wt_h[2], Wt_l[2], bv,
                     ESC_PROJ, 1.0f, Vf, (f16*)nullptr, (f16*)nullptr, Bn * Ln, Dn, Dn);
  hipLaunchKernelGGL(tsplit_v, dim3(Ln / 64, BHn), blk, 0, stream, Vf, Vth, Vtl);
  hipLaunchKernelGGL(ksum_kernel, dim3(BHn), blk, 0, stream, Kbh, Kbl, ksum);
  hipLaunchKernelGGL(attn_stats_mfma, dim3(Ln / 128, BHn), blk, 0, stream,
                     Qbh, Qbl, Kbh, Kbl, ksum, rowmax, spars);
  hipLaunchKernelGGL(topk_sort, dim3(BHn), blk, 0, stream, spars, topi, wrow);
  hipLaunchKernelGGL(refine_rows, dim3(16, BHn), blk, 0, stream, Qf, Kf, wrow, spx);
  hipLaunchKernelGGL(topk_final, dim3(BHn), dim3(64), 0, stream, spx, wrow, topi);
  hipMemsetAsync(AOh, 0, NE * 2, stream);
  hipMemsetAsync(AOl, 0, NE * 2, stream);
  hipLaunchKernelGGL(attn_sel_mfma, dim3((Un + 63) / 64, BHn), blk, 0, stream,
                     Qbh, Qbl, Kbh, Kbl, Vth, Vtl, topi, rowmax, AOh, AOl);
  hipLaunchKernelGGL(gemm_split, gg, blk, 0, stream, AOh, AOl, Wt_h[3], Wt_l[3], bo,
                     ESC_OUT, 1.0f, out, (f16*)nullptr, (f16*)nullptr, Bn * Ln, Dn, Dn);
}

// Round 5
// 528.262 us; speedup vs baseline: 2.9855x; 1.2336x over previous
//
#include <hip/hip_runtime.h>
#include <math.h>
#include <stdint.h>

#define Bn 2
#define Ln 2048
#define Dn 1024
#define Hn 16
#define DHn 64
#define Un 1228
#define BHn (Bn*Hn)
#define SCALE 0.125f
// pre-split power-of-2 scales (dodge fp16 subnormal flush on lo terms)
#define SXf 16.0f     // x
#define SWf 256.0f    // all W
#define SQf 16.0f     // Q, K
#define SVf 16.0f     // V
#define SPf 16.0f     // softmax P
#define ESC_PROJ (1.0f / 4096.0f)    // 1/(SX*SW)
#define ESC_OUT  (1.0f / 65536.0f)   // 1/(SA*SW), SA = SPf*SVf = 256
#define PSC (SCALE / 256.0f)         // score unscale: 1/(SQ*SQ) * SCALE

typedef _Float16 f16;
typedef __attribute__((ext_vector_type(8))) _Float16 f16x8;
typedef __attribute__((ext_vector_type(4))) float f32x4;
struct h4s { f16 x, y, z, w; };

__device__ __forceinline__ void splitf16(float f, f16& hi, f16& lo) {
  hi = (f16)f;                 // RTNE
  lo = (f16)(f - (float)hi);   // residual, ~22 mantissa bits total
}

// async global->LDS, 16B per lane (wave-uniform base + lane*16)
__device__ __forceinline__ void gl_lds16(const void* g, void* l) {
  __builtin_amdgcn_global_load_lds(
      (const __attribute__((address_space(1))) void*)g,
      (__attribute__((address_space(3))) void*)l, 16, 0, 0);
}

#define MFMA(a, b, c) __builtin_amdgcn_mfma_f32_16x16x32_f16((a), (b), (c), 0, 0, 0)

// ---------------- split x*16 -> xh, xl ----------------
__global__ __launch_bounds__(256) void split_kernel(
    const float* __restrict__ in, f16* __restrict__ oh, f16* __restrict__ ol, int n4) {
  int i = blockIdx.x * 256 + threadIdx.x;
  if (i >= n4) return;
  float4 v = ((const float4*)in)[i];
  h4s h, l;
  splitf16(v.x * SXf, h.x, l.x); splitf16(v.y * SXf, h.y, l.y);
  splitf16(v.z * SXf, h.z, l.z); splitf16(v.w * SXf, h.w, l.w);
  ((h4s*)oh)[i] = h; ((h4s*)ol)[i] = l;
}

// ---------------- transpose + split W*256: W[k][n] -> Wt[n][k] hi/lo ----------------
__global__ __launch_bounds__(256) void tsplit_w(
    const float* __restrict__ in, f16* __restrict__ oh, f16* __restrict__ ol) {
  __shared__ float ts[64][65];
  const int t = threadIdx.x;
  const int r0 = blockIdx.x * 64, c0 = blockIdx.y * 64;
#pragma unroll
  for (int c = 0; c < 4; ++c) {
    int f = (c * 256 + t) * 4; int row = f >> 6, col = f & 63;
    float4 v = *(const float4*)&in[(size_t)(r0 + row) * Dn + c0 + col];
    ts[row][col] = v.x; ts[row][col + 1] = v.y; ts[row][col + 2] = v.z; ts[row][col + 3] = v.w;
  }
  __syncthreads();
#pragma unroll
  for (int c = 0; c < 4; ++c) {
    int f = (c * 256 + t) * 4; int crow = f >> 6, rcol = f & 63;
    h4s h, l;
    splitf16(ts[rcol + 0][crow] * SWf, h.x, l.x);
    splitf16(ts[rcol + 1][crow] * SWf, h.y, l.y);
    splitf16(ts[rcol + 2][crow] * SWf, h.z, l.z);
    splitf16(ts[rcol + 3][crow] * SWf, h.w, l.w);
    size_t o = (size_t)(c0 + crow) * Dn + r0 + rcol;
    *(h4s*)&oh[o] = h; *(h4s*)&ol[o] = l;
  }
}

// ---------------- transpose V*16 (single fp16): V[b,l,D] -> Vt[bh*64+d][L] ----------------
__global__ __launch_bounds__(256) void tsplit_v(
    const float* __restrict__ Vf, f16* __restrict__ oh) {
  __shared__ float ts[64][65];
  const int t = threadIdx.x;
  const int l0 = blockIdx.x * 64;
  const int bh = blockIdx.y, b = bh >> 4, h = bh & 15;
#pragma unroll
  for (int c = 0; c < 4; ++c) {
    int f = (c * 256 + t) * 4; int lrow = f >> 6, dcol = f & 63;
    float4 v = *(const float4*)&Vf[((size_t)b * Ln + l0 + lrow) * Dn + h * DHn + dcol];
    ts[lrow][dcol] = v.x; ts[lrow][dcol + 1] = v.y; ts[lrow][dcol + 2] = v.z; ts[lrow][dcol + 3] = v.w;
  }
  __syncthreads();
#pragma unroll
  for (int c = 0; c < 4; ++c) {
    int f = (c * 256 + t) * 4; int drow = f >> 6, lcol = f & 63;
    h4s h4;
    h4.x = (f16)(ts[lcol + 0][drow] * SVf);
    h4.y = (f16)(ts[lcol + 1][drow] * SVf);
    h4.z = (f16)(ts[lcol + 2][drow] * SVf);
    h4.w = (f16)(ts[lcol + 3][drow] * SVf);
    size_t o = ((size_t)bh * DHn + drow) * Ln + l0 + lcol;
    *(h4s*)&oh[o] = h4;
  }
}

// ---------------- split-fp16 MFMA GEMM: C = (A @ Bt^T)*escale + bias (3-MFMA) ----------------
__global__ __launch_bounds__(256) void gemm_split(
    const f16* __restrict__ Ah, const f16* __restrict__ Al,
    const f16* __restrict__ Bth, const f16* __restrict__ Btl,
    const float* __restrict__ bias, float escale, float osplit,
    float* __restrict__ Cf, f16* __restrict__ Ch, f16* __restrict__ Cl,
    int M, int N, int K) {
  __shared__ f16 sAh[128 * 32], sAl[128 * 32], sBh[128 * 32], sBl[128 * 32];
  const int t = threadIdx.x;
  const int w = t >> 6, lane = t & 63, lm = lane & 15, q = lane >> 4;
  const int wr = w >> 1, wc = w & 1;
  const int n0 = blockIdx.x * 128, m0 = blockIdx.y * 128;
  f32x4 acc[4][4] = {};
  for (int k0 = 0; k0 < K; k0 += 32) {
    const f16* s0 = Ah + (size_t)m0 * K + k0;
    const f16* s1 = Al + (size_t)m0 * K + k0;
    const f16* s2 = Bth + (size_t)n0 * K + k0;
    const f16* s3 = Btl + (size_t)n0 * K + k0;
#pragma unroll
    for (int c = 0; c < 2; ++c) {
      int f = (c * 256 + t) * 8; int row = f >> 5, col = f & 31;
      size_t go = (size_t)row * K + col;
      gl_lds16(s0 + go, &sAh[f]);
      gl_lds16(s1 + go, &sAl[f]);
      gl_lds16(s2 + go, &sBh[f]);
      gl_lds16(s3 + go, &sBl[f]);
    }
    __syncthreads();
    f16x8 a_h[4], a_l[4], b_h[4], b_l[4];
#pragma unroll
    for (int mi = 0; mi < 4; ++mi) {
      int r = (wr * 64 + mi * 16 + lm) * 32 + q * 8;
      a_h[mi] = *(const f16x8*)&sAh[r];
      a_l[mi] = *(const f16x8*)&sAl[r];
    }
#pragma unroll
    for (int ni = 0; ni < 4; ++ni) {
      int r = (wc * 64 + ni * 16 + lm) * 32 + q * 8;
      b_h[ni] = *(const f16x8*)&sBh[r];
      b_l[ni] = *(const f16x8*)&sBl[r];
    }
#pragma unroll
    for (int mi = 0; mi < 4; ++mi)
#pragma unroll
      for (int ni = 0; ni < 4; ++ni) {
        acc[mi][ni] = MFMA(a_h[mi], b_h[ni], acc[mi][ni]);
        acc[mi][ni] = MFMA(a_h[mi], b_l[ni], acc[mi][ni]);
        acc[mi][ni] = MFMA(a_l[mi], b_h[ni], acc[mi][ni]);
      }
    __syncthreads();
  }
#pragma unroll
  for (int mi = 0; mi < 4; ++mi)
#pragma unroll
    for (int ni = 0; ni < 4; ++ni) {
      int gcol = n0 + wc * 64 + ni * 16 + lm;
      float bv = bias[gcol];
#pragma unroll
      for (int r = 0; r < 4; ++r) {
        int grow = m0 + wr * 64 + mi * 16 + q * 4 + r;
        float v = acc[mi][ni][r] * escale + bv;
        size_t o = (size_t)grow * N + gcol;
        if (Cf) Cf[o] = v;
        if (Ch) { f16 hh, ll; splitf16(v * osplit, hh, ll); Ch[o] = hh; Cl[o] = ll; }
      }
    }
}

// ---------------- A-single MFMA GEMM: C = (A @ Bt^T)*escale + bias (2-MFMA) ----------------
__global__ __launch_bounds__(256, 3) void gemm_a1(
    const f16* __restrict__ A,
    const f16* __restrict__ Bth, const f16* __restrict__ Btl,
    const float* __restrict__ bias, float escale,
    float* __restrict__ Cf, int M, int N, int K) {
  __shared__ f16 sA[128 * 32], sBh[128 * 32], sBl[128 * 32];
  const int t = threadIdx.x;
  const int w = t >> 6, lane = t & 63, lm = lane & 15, q = lane >> 4;
  const int wr = w >> 1, wc = w & 1;
  const int n0 = blockIdx.x * 128, m0 = blockIdx.y * 128;
  f32x4 acc[4][4] = {};
  for (int k0 = 0; k0 < K; k0 += 32) {
    const f16* s0 = A + (size_t)m0 * K + k0;
    const f16* s2 = Bth + (size_t)n0 * K + k0;
    const f16* s3 = Btl + (size_t)n0 * K + k0;
#pragma unroll
    for (int c = 0; c < 2; ++c) {
      int f = (c * 256 + t) * 8; int row = f >> 5, col = f & 31;
      size_t go = (size_t)row * K + col;
      gl_lds16(s0 + go, &sA[f]);
      gl_lds16(s2 + go, &sBh[f]);
      gl_lds16(s3 + go, &sBl[f]);
    }
    __syncthreads();
    f16x8 a_[4], b_h[4], b_l[4];
#pragma unroll
    for (int mi = 0; mi < 4; ++mi)
      a_[mi] = *(const f16x8*)&sA[(wr * 64 + mi * 16 + lm) * 32 + q * 8];
#pragma unroll
    for (int ni = 0; ni < 4; ++ni) {
      int r = (wc * 64 + ni * 16 + lm) * 32 + q * 8;
      b_h[ni] = *(const f16x8*)&sBh[r];
      b_l[ni] = *(const f16x8*)&sBl[r];
    }
#pragma unroll
    for (int mi = 0; mi < 4; ++mi)
#pragma unroll
      for (int ni = 0; ni < 4; ++ni) {
        acc[mi][ni] = MFMA(a_[mi], b_h[ni], acc[mi][ni]);
        acc[mi][ni] = MFMA(a_[mi], b_l[ni], acc[mi][ni]);
      }
    __syncthreads();
  }
#pragma unroll
  for (int mi = 0; mi < 4; ++mi)
#pragma unroll
    for (int ni = 0; ni < 4; ++ni) {
      int gcol = n0 + wc * 64 + ni * 16 + lm;
      float bv = bias[gcol];
#pragma unroll
      for (int r = 0; r < 4; ++r) {
        int grow = m0 + wr * 64 + mi * 16 + q * 4 + r;
        Cf[(size_t)grow * N + gcol] = acc[mi][ni][r] * escale + bv;
      }
    }
}

// ---------------- ksum[bh][d] = sum_l K'[b,l,h*64+d] ----------------
__global__ __launch_bounds__(256) void ksum_kernel(
    const f16* __restrict__ Kh, const f16* __restrict__ Kl, float* __restrict__ ksum) {
  __shared__ float red[4][64];
  const int t = threadIdx.x, d = t & 63, seg = t >> 6;
  const int bh = blockIdx.x, b = bh >> 4, h = bh & 15;
  float s = 0.f;
  for (int l = seg * 512; l < (seg + 1) * 512; ++l) {
    size_t o = ((size_t)b * Ln + l) * Dn + h * DHn + d;
    s += (float)Kh[o] + (float)Kl[o];
  }
  red[seg][d] = s;
  __syncthreads();
  if (t < 64) ksum[bh * DHn + t] = red[0][t] + red[1][t] + red[2][t] + red[3][t];
}

// ---------------- stats: approx row max (MFMA, split) + spars = max - mean ----------------
// Q-frags hoisted to registers (invariant across K-tiles): per-iter LDS reads = 8 b128.
__global__ __launch_bounds__(256, 2) void attn_stats_mfma(
    const f16* __restrict__ Qh, const f16* __restrict__ Ql,
    const f16* __restrict__ Kh, const f16* __restrict__ Kl,
    const float* __restrict__ ksum,
    float* __restrict__ row_max, float* __restrict__ spars) {
  __shared__ f16 sQh[128 * 64], sQl[128 * 64], sKh[128 * 64], sKl[128 * 64];
  __shared__ float redm[128][5];
  const int t = threadIdx.x;
  const int w = t >> 6, lane = t & 63, lm = lane & 15, q = lane >> 4;
  const int bh = blockIdx.y, b = bh >> 4, h = bh & 15;
  const int q0 = blockIdx.x * 128;
  const f16* qsh = Qh + ((size_t)b * Ln + q0) * Dn + h * DHn;
  const f16* qsl = Ql + ((size_t)b * Ln + q0) * Dn + h * DHn;
#pragma unroll
  for (int c = 0; c < 4; ++c) {
    int f = (c * 256 + t) * 8; int row = f >> 6, col = f & 63;
    size_t go = (size_t)row * Dn + col;
    gl_lds16(qsh + go, &sQh[f]);
    gl_lds16(qsl + go, &sQl[f]);
  }
  __syncthreads();
  // hoist all Q fragments (8 mi x 2 ks, hi+lo) into registers
  f16x8 a_h[8][2], a_l[8][2];
#pragma unroll
  for (int mi = 0; mi < 8; ++mi)
#pragma unroll
    for (int ks = 0; ks < 2; ++ks) {
      int r = (mi * 16 + lm) * 64 + ks * 32 + q * 8;
      a_h[mi][ks] = *(const f16x8*)&sQh[r];
      a_l[mi][ks] = *(const f16x8*)&sQl[r];
    }
  float rmax[8][4];
#pragma unroll
  for (int mi = 0; mi < 8; ++mi)
#pragma unroll
    for (int r = 0; r < 4; ++r) rmax[mi][r] = -1e30f;

  for (int kt = 0; kt < Ln / 128; ++kt) {
    __syncthreads();
    const f16* ksh = Kh + ((size_t)b * Ln + kt * 128) * Dn + h * DHn;
    const f16* ksl = Kl + ((size_t)b * Ln + kt * 128) * Dn + h * DHn;
#pragma unroll
    for (int c = 0; c < 4; ++c) {
      int f = (c * 256 + t) * 8; int row = f >> 6, col = f & 63;
      size_t go = (size_t)row * Dn + col;
      gl_lds16(ksh + go, &sKh[f]);
      gl_lds16(ksl + go, &sKl[f]);
    }
    __syncthreads();
#pragma unroll
    for (int ni = 0; ni < 2; ++ni) {
      int bcol = (w * 2 + ni) * 16;
      f16x8 b_h[2], b_l[2];
#pragma unroll
      for (int ks = 0; ks < 2; ++ks) {
        int r = (bcol + lm) * 64 + ks * 32 + q * 8;
        b_h[ks] = *(const f16x8*)&sKh[r];
        b_l[ks] = *(const f16x8*)&sKl[r];
      }
#pragma unroll
      for (int mi = 0; mi < 8; ++mi) {
        f32x4 acc = {0.f, 0.f, 0.f, 0.f};
#pragma unroll
        for (int ks = 0; ks < 2; ++ks) {
          acc = MFMA(a_h[mi][ks], b_h[ks], acc);
          acc = MFMA(a_h[mi][ks], b_l[ks], acc);
          acc = MFMA(a_l[mi][ks], b_h[ks], acc);
        }
#pragma unroll
        for (int r = 0; r < 4; ++r) rmax[mi][r] = fmaxf(rmax[mi][r], acc[r]);
      }
    }
  }
#pragma unroll
  for (int mi = 0; mi < 8; ++mi)
#pragma unroll
    for (int r = 0; r < 4; ++r) {
      float v = rmax[mi][r];
      v = fmaxf(v, __shfl_xor(v, 1)); v = fmaxf(v, __shfl_xor(v, 2));
      v = fmaxf(v, __shfl_xor(v, 4)); v = fmaxf(v, __shfl_xor(v, 8));
      if (lm == 0) redm[mi * 16 + q * 4 + r][w] = v;
    }
  __syncthreads();
  if (t < 128) {
    float m = fmaxf(fmaxf(redm[t][0], redm[t][1]), fmaxf(redm[t][2], redm[t][3]));
    float dot = 0.f;
    const float* kp = ksum + bh * DHn;
#pragma unroll
    for (int d = 0; d < 64; ++d)
      dot += ((float)sQh[t * 64 + d] + (float)sQl[t * 64 + d]) * kp[d];
    row_max[(size_t)bh * Ln + q0 + t] = m * PSC;
    spars[(size_t)bh * Ln + q0 + t] = m * PSC - dot * (PSC / (float)Ln);
  }
}

// ---------------- bitonic sort on approx spars; bulk top + 16-row boundary window ----------------
__global__ __launch_bounds__(256) void topk_sort(
    const float* __restrict__ spars, int* __restrict__ top_idx, int* __restrict__ wrow) {
  __shared__ unsigned long long keys[Ln];   // 16 KB
  const int t = threadIdx.x;
  const int bh = blockIdx.x;
  for (int i = t; i < Ln; i += 256) {
    unsigned u = __float_as_uint(spars[(size_t)bh * Ln + i]);
    u = (u & 0x80000000u) ? ~u : (u | 0x80000000u);
    u = ~u;
    keys[i] = ((unsigned long long)u << 32) | (unsigned)i;
  }
  __syncthreads();
  for (unsigned k = 2; k <= Ln; k <<= 1) {
    for (unsigned j = k >> 1; j > 0; j >>= 1) {
#pragma unroll
      for (int p = 0; p < Ln / 256; ++p) {
        int i = p * 256 + t;
        int ixj = i ^ (int)j;
        if (ixj > i) {
          unsigned long long a = keys[i], bb = keys[ixj];
          bool up = ((i & (int)k) == 0);
          if ((a > bb) == up) { keys[i] = bb; keys[ixj] = a; }
        }
      }
      __syncthreads();
    }
  }
  for (int u = t; u < Un - 8; u += 256)
    top_idx[(size_t)bh * Un + u] = (int)(keys[u] & 0xFFFFFFFFu);
  if (t < 16) wrow[bh * 16 + t] = (int)(keys[Un - 8 + t] & 0xFFFFFFFFu);
}

// ---------------- exact fp32 sparsity for one window row per block ----------------
__global__ __launch_bounds__(256) void refine_rows(
    const float* __restrict__ Qf, const float* __restrict__ Kf,
    const int* __restrict__ wrow, float* __restrict__ spx) {
  __shared__ float qs[64];
  __shared__ float redm[4], reds[4];
  const int t = threadIdx.x;
  const int j = blockIdx.x, bh = blockIdx.y, b = bh >> 4, h = bh & 15;
  const int qi = wrow[bh * 16 + j];
  if (t < 64) qs[t] = Qf[((size_t)b * Ln + qi) * Dn + h * DHn + t];
  __syncthreads();
  float mx = -1e30f, sm = 0.f;
  for (int ki = t; ki < Ln; ki += 256) {
    const float* kp = &Kf[((size_t)b * Ln + ki) * Dn + h * DHn];
    float s = 0.f;
#pragma unroll
    for (int d0 = 0; d0 < 64; d0 += 4) {
      float4 k4 = *(const float4*)&kp[d0];
      s = fmaf(k4.x, qs[d0], s);
      s = fmaf(k4.y, qs[d0 + 1], s);
      s = fmaf(k4.z, qs[d0 + 2], s);
      s = fmaf(k4.w, qs[d0 + 3], s);
    }
    mx = fmaxf(mx, s); sm += s;
  }
  const int w = t >> 6, lane = t & 63;
#pragma unroll
  for (int off = 1; off < 64; off <<= 1) {
    mx = fmaxf(mx, __shfl_xor(mx, off));
    sm += __shfl_xor(sm, off);
  }
  if (lane == 0) { redm[w] = mx; reds[w] = sm; }
  __syncthreads();
  if (t == 0) {
    float m = fmaxf(fmaxf(redm[0], redm[1]), fmaxf(redm[2], redm[3]));
    float s = reds[0] + reds[1] + reds[2] + reds[3];
    spx[bh * 16 + j] = SCALE * (m - s * (1.0f / (float)Ln));
  }
}

// ---------------- pick top-8 of the 16 window rows (exact values) ----------------
__global__ __launch_bounds__(64) void topk_final(
    const float* __restrict__ spx, const int* __restrict__ wrow,
    int* __restrict__ top_idx) {
  const int bh = blockIdx.x;
  if (threadIdx.x != 0) return;
  float v[16]; int r[16];
#pragma unroll
  for (int j = 0; j < 16; ++j) { v[j] = spx[bh * 16 + j]; r[j] = wrow[bh * 16 + j]; }
  unsigned taken = 0;
  for (int s = 0; s < 8; ++s) {
    int best = -1;
    for (int j = 0; j < 16; ++j) {
      if (taken & (1u << j)) continue;
      if (best < 0 || v[j] > v[best] || (v[j] == v[best] && r[j] < r[best])) best = j;
    }
    taken |= 1u << best;
    top_idx[(size_t)bh * Un + (Un - 8) + s] = r[best];
  }
}

// ---------------- selected-row attention, single-fp16 MFMA, hoisted Q ----------------
// LDS: sK 8K + sV 8K + sQP 10K (Q stage then P, stride 80) ~ 26.5 KB.
__global__ __launch_bounds__(256, 4) void attn_sel_mfma(
    const f16* __restrict__ Qh, const f16* __restrict__ Kh,
    const f16* __restrict__ Vth,
    const int* __restrict__ topi, const float* __restrict__ row_max,
    f16* __restrict__ AOh) {
  __shared__ f16 sK[64 * 64], sV[64 * 64];
  __shared__ f16 sQP[64 * 80];   // Q staged (stride 80), then P (stride 80)
  __shared__ float rmL[64];
  __shared__ int qxL[64];
  __shared__ float dred[64][5];
  const int t = threadIdx.x;
  const int w = t >> 6, lane = t & 63, lm = lane & 15, q = lane >> 4;
  const int bh = blockIdx.y, b = bh >> 4, h = bh & 15;
  const int u0 = blockIdx.x * 64;
  const int nrows = (Un - u0 < 64) ? (Un - u0) : 64;
  if (t < 64) {
    int qi = topi[(size_t)bh * Un + ((t < nrows) ? (u0 + t) : 0)];
    qxL[t] = qi;
    rmL[t] = row_max[(size_t)bh * Ln + qi];
  }
  __syncthreads();
  // gather selected Q rows (single fp16) into sQP (stride 80)
#pragma unroll
  for (int c = 0; c < 2; ++c) {
    int f = (c * 256 + t) * 8; int row = f >> 6, col = f & 63;
    size_t go = ((size_t)b * Ln + qxL[row]) * Dn + h * DHn + col;
    *(uint4*)&sQP[row * 80 + col] = *(const uint4*)&Qh[go];
  }
  __syncthreads();
  // hoist Q fragments (4 mi x 2 ks) into registers; sQP is then reused for P
  f16x8 aq[4][2];
#pragma unroll
  for (int mi = 0; mi < 4; ++mi)
#pragma unroll
    for (int ks = 0; ks < 2; ++ks)
      aq[mi][ks] = *(const f16x8*)&sQP[(mi * 16 + lm) * 80 + ks * 32 + q * 8];
  f32x4 oacc[4] = {};
  float dacc[4][4] = {};

  const f16* kbase = Kh + (size_t)b * Ln * Dn + h * DHn;
  const f16* vbase = Vth + (size_t)bh * DHn * Ln;
  for (int kt = 0; kt < Ln / 64; ++kt) {
    const int l0 = kt * 64;
    __syncthreads();   // prev iter PV reads done; K/V/P free for overwrite
#pragma unroll
    for (int c = 0; c < 2; ++c) {
      int f = (c * 256 + t) * 8; int row = f >> 6, col = f & 63;
      gl_lds16(kbase + (size_t)(l0 + row) * Dn + col, &sK[f]);
      gl_lds16(vbase + (size_t)row * Ln + l0 + col, &sV[f]);
    }
    __syncthreads();   // staging complete
    // S = Q K^T (wave w covers key cols w*16..w*16+15)
    f16x8 kb[2];
#pragma unroll
    for (int ks = 0; ks < 2; ++ks)
      kb[ks] = *(const f16x8*)&sK[(w * 16 + lm) * 64 + ks * 32 + q * 8];
#pragma unroll
    for (int mi = 0; mi < 4; ++mi) {
      f32x4 acc = {0.f, 0.f, 0.f, 0.f};
      acc = MFMA(aq[mi][0], kb[0], acc);
      acc = MFMA(aq[mi][1], kb[1], acc);
#pragma unroll
      for (int r = 0; r < 4; ++r) {
        int row = mi * 16 + q * 4 + r;
        float p = __expf(acc[r] * PSC - rmL[row]);   // rm ~ true max -> p <= ~1
        dacc[mi][r] += p;
        sQP[row * 80 + w * 16 + lm] = (f16)(p * SPf);
      }
    }
    __syncthreads();   // P ready
    // O += P @ V (wave w covers out dims d = w*16..w*16+15)
    f16x8 vb[2];
#pragma unroll
    for (int ks = 0; ks < 2; ++ks)
      vb[ks] = *(const f16x8*)&sV[(w * 16 + lm) * 64 + ks * 32 + q * 8];
#pragma unroll
    for (int mi = 0; mi < 4; ++mi) {
#pragma unroll
      for (int ks = 0; ks < 2; ++ks) {
        f16x8 pf = *(const f16x8*)&sQP[(mi * 16 + lm) * 80 + ks * 32 + q * 8];
        oacc[mi] = MFMA(pf, vb[ks], oacc[mi]);
      }
    }
  }
#pragma unroll
  for (int mi = 0; mi < 4; ++mi)
#pragma unroll
    for (int r = 0; r < 4; ++r) {
      float v = dacc[mi][r];
      v += __shfl_xor(v, 1); v += __shfl_xor(v, 2);
      v += __shfl_xor(v, 4); v += __shfl_xor(v, 8);
      if (lm == 0) dred[mi * 16 + q * 4 + r][w] = v;
    }
  __syncthreads();
#pragma unroll
  for (int mi = 0; mi < 4; ++mi)
#pragma unroll
    for (int r = 0; r < 4; ++r) {
      int row = mi * 16 + q * 4 + r;
      if (row < nrows) {
        // oacc = SPf*SVf*sum(p v) = 256*sum(p v); dred = sum(p); ESC_OUT folds 256*SWf
        float dinv = 1.0f / (dred[row][0] + dred[row][1] + dred[row][2] + dred[row][3]);
        size_t o = ((size_t)b * Ln + qxL[row]) * Dn + h * DHn + w * 16 + lm;
        AOh[o] = (f16)(oacc[mi][r] * dinv);
      }
    }
}

extern "C" void kernel_launch(void* const* d_in, const int* in_sizes, int n_in,
                              void* d_out, int out_size, void* d_ws, size_t ws_size,
                              hipStream_t stream) {
  (void)in_sizes; (void)n_in; (void)out_size; (void)ws_size;
  const float* x  = (const float*)d_in[0];
  const float* Wq = (const float*)d_in[1];
  const float* bq = (const float*)d_in[2];
  const float* Wk = (const float*)d_in[3];
  const float* bk = (const float*)d_in[4];
  const float* Wv = (const float*)d_in[5];
  const float* bv = (const float*)d_in[6];
  const float* Wo = (const float*)d_in[7];
  const float* bo = (const float*)d_in[8];
  float* out = (float*)d_out;

  uint8_t* p = (uint8_t*)d_ws;
  const size_t NE = (size_t)Bn * Ln * Dn;          // 4 Mi elements
  f16* xh = (f16*)p;  p += NE * 2;
  f16* xl = (f16*)p;  p += NE * 2;
  f16* Wt_h[4]; f16* Wt_l[4];
  for (int i = 0; i < 4; ++i) {
    Wt_h[i] = (f16*)p; p += (size_t)Dn * Dn * 2;
    Wt_l[i] = (f16*)p; p += (size_t)Dn * Dn * 2;
  }
  f16* Qbh = (f16*)p; p += NE * 2;
  f16* Qbl = (f16*)p; p += NE * 2;
  f16* Kbh = (f16*)p; p += NE * 2;
  f16* Kbl = (f16*)p; p += NE * 2;
  float* Qf = (float*)p;  p += NE * 4;
  float* Kf = (float*)p;  p += NE * 4;
  float* Vf = (float*)p;  p += NE * 4;
  f16* Vth = (f16*)p; p += NE * 2;
  float* rowmax = (float*)p; p += (size_t)BHn * Ln * 4;
  float* spars  = (float*)p; p += (size_t)BHn * Ln * 4;
  float* ksum   = (float*)p; p += (size_t)BHn * DHn * 4;
  int* topi     = (int*)p;   p += (size_t)BHn * Un * 4;
  int* wrow     = (int*)p;   p += (size_t)BHn * 16 * 4;
  float* spx    = (float*)p; p += (size_t)BHn * 16 * 4;
  f16* AOh = xh;   // alias: x split dead after V-GEMM

  dim3 blk(256);
  hipLaunchKernelGGL(split_kernel, dim3((int)(NE / 4 / 256)), blk, 0, stream, x, xh, xl, (int)(NE / 4));
  hipLaunchKernelGGL(tsplit_w, dim3(16, 16), blk, 0, stream, Wq, Wt_h[0], Wt_l[0]);
  hipLaunchKernelGGL(tsplit_w, dim3(16, 16), blk, 0, stream, Wk, Wt_h[1], Wt_l[1]);
  hipLaunchKernelGGL(tsplit_w, dim3(16, 16), blk, 0, stream, Wv, Wt_h[2], Wt_l[2]);
  hipLaunchKernelGGL(tsplit_w, dim3(16, 16), blk, 0, stream, Wo, Wt_h[3], Wt_l[3]);

  dim3 gg(Dn / 128, (Bn * Ln) / 128);
  hipLaunchKernelGGL(gemm_split, gg, blk, 0, stream, xh, xl, Wt_h[0], Wt_l[0], bq,
                     ESC_PROJ, SQf, Qf, Qbh, Qbl, Bn * Ln, Dn, Dn);
  hipLaunchKernelGGL(gemm_split, gg, blk, 0, stream, xh, xl, Wt_h[1], Wt_l[1], bk,
                     ESC_PROJ, SQf, Kf, Kbh, Kbl, Bn * Ln, Dn, Dn);
  hipLaunchKernelGGL(gemm_split, gg, blk, 0, stream, xh, xl, Wt_h[2], Wt_l[2], bv,
                     ESC_PROJ, 1.0f, Vf, (f16*)nullptr, (f16*)nullptr, Bn * Ln, Dn, Dn);
  hipLaunchKernelGGL(tsplit_v, dim3(Ln / 64, BHn), blk, 0, stream, Vf, Vth);
  hipLaunchKernelGGL(ksum_kernel, dim3(BHn), blk, 0, stream, Kbh, Kbl, ksum);
  hipLaunchKernelGGL(attn_stats_mfma, dim3(Ln / 128, BHn), blk, 0, stream,
                     Qbh, Qbl, Kbh, Kbl, ksum, rowmax, spars);
  hipLaunchKernelGGL(topk_sort, dim3(BHn), blk, 0, stream, spars, topi, wrow);
  hipLaunchKernelGGL(refine_rows, dim3(16, BHn), blk, 0, stream, Qf, Kf, wrow, spx);
  hipLaunchKernelGGL(topk_final, dim3(BHn), dim3(64), 0, stream, spx, wrow, topi);
  hipMemsetAsync(AOh, 0, NE * 2, stream);
  hipLaunchKernelGGL(attn_sel_mfma, dim3((Un + 63) / 64, BHn), blk, 0, stream,
                     Qbh, Kbh, Vth, topi, rowmax, AOh);
  hipLaunchKernelGGL(gemm_a1, gg, blk, 0, stream, AOh, Wt_h[3], Wt_l[3], bo,
                     ESC_OUT, out, Bn * Ln, Dn, Dn);
}

// Round 6
// 406.675 us; speedup vs baseline: 3.8781x; 1.2990x over previous
//
#include <hip/hip_runtime.h>
#include <math.h>
#include <stdint.h>

#define Bn 2
#define Ln 2048
#define Dn 1024
#define Hn 16
#define DHn 64
#define Un 1228
#define BHn (Bn*Hn)
#define SCALE 0.125f
// pre-split power-of-2 scales (dodge fp16 subnormal flush on lo terms)
#define SXf 16.0f     // x
#define SWf 256.0f    // all W
#define SQf 16.0f     // Q, K
#define SVf 16.0f     // V
#define SPf 16.0f     // softmax P
#define ESC_PROJ (1.0f / 4096.0f)    // 1/(SX*SW)
#define ESC_OUT  (1.0f / 65536.0f)   // 1/(SPf*SVf*SWf)
#define PSC (SCALE / 256.0f)         // score unscale: 1/(SQ*SQ) * SCALE

typedef _Float16 f16;
typedef __attribute__((ext_vector_type(8))) _Float16 f16x8;
typedef __attribute__((ext_vector_type(4))) float f32x4;
struct h4s { f16 x, y, z, w; };

__device__ __forceinline__ void splitf16(float f, f16& hi, f16& lo) {
  hi = (f16)f;                 // RTNE
  lo = (f16)(f - (float)hi);   // residual, ~22 mantissa bits total
}

// async global->LDS, 16B per lane (wave-uniform base + lane*16)
__device__ __forceinline__ void gl_lds16(const void* g, void* l) {
  __builtin_amdgcn_global_load_lds(
      (const __attribute__((address_space(1))) void*)g,
      (__attribute__((address_space(3))) void*)l, 16, 0, 0);
}

#define MFMA(a, b, c) __builtin_amdgcn_mfma_f32_16x16x32_f16((a), (b), (c), 0, 0, 0)

// ---------------- split x*16 -> xh, xl ----------------
__global__ __launch_bounds__(256) void split_kernel(
    const float* __restrict__ in, f16* __restrict__ oh, f16* __restrict__ ol, int n4) {
  int i = blockIdx.x * 256 + threadIdx.x;
  if (i >= n4) return;
  float4 v = ((const float4*)in)[i];
  h4s h, l;
  splitf16(v.x * SXf, h.x, l.x); splitf16(v.y * SXf, h.y, l.y);
  splitf16(v.z * SXf, h.z, l.z); splitf16(v.w * SXf, h.w, l.w);
  ((h4s*)oh)[i] = h; ((h4s*)ol)[i] = l;
}

// ------- transpose + split W*256 for all 4 weights: Wt[z*1024 + n][k] hi/lo -------
__global__ __launch_bounds__(256) void tsplit_w4(
    const float* __restrict__ W0, const float* __restrict__ W1,
    const float* __restrict__ W2, const float* __restrict__ W3,
    f16* __restrict__ oh, f16* __restrict__ ol) {
  __shared__ float ts[64][65];
  const int t = threadIdx.x;
  const int r0 = blockIdx.x * 64, c0 = blockIdx.y * 64;
  const int z = blockIdx.z;
  const float* in = (z == 0) ? W0 : (z == 1) ? W1 : (z == 2) ? W2 : W3;
#pragma unroll
  for (int c = 0; c < 4; ++c) {
    int f = (c * 256 + t) * 4; int row = f >> 6, col = f & 63;
    float4 v = *(const float4*)&in[(size_t)(r0 + row) * Dn + c0 + col];
    ts[row][col] = v.x; ts[row][col + 1] = v.y; ts[row][col + 2] = v.z; ts[row][col + 3] = v.w;
  }
  __syncthreads();
#pragma unroll
  for (int c = 0; c < 4; ++c) {
    int f = (c * 256 + t) * 4; int crow = f >> 6, rcol = f & 63;
    h4s h, l;
    splitf16(ts[rcol + 0][crow] * SWf, h.x, l.x);
    splitf16(ts[rcol + 1][crow] * SWf, h.y, l.y);
    splitf16(ts[rcol + 2][crow] * SWf, h.z, l.z);
    splitf16(ts[rcol + 3][crow] * SWf, h.w, l.w);
    size_t o = (size_t)(z * 1024 + c0 + crow) * Dn + r0 + rcol;
    *(h4s*)&oh[o] = h; *(h4s*)&ol[o] = l;
  }
}

// ------- fused QKV GEMM: [4096 x 3072] = x @ [Wq|Wk|Wv]^T, segment-wise epilogue -------
__global__ void gemm_qkv(
    const f16* __restrict__ Ah, const f16* __restrict__ Al,
    const f16* __restrict__ Bth, const f16* __restrict__ Btl,
    const float* __restrict__ bq, const float* __restrict__ bk, const float* __restrict__ bv,
    float* __restrict__ Qf, f16* __restrict__ Qbh, f16* __restrict__ Qbl,
    float* __restrict__ Kf, f16* __restrict__ Kbh, f16* __restrict__ Kbl,
    f16* __restrict__ Vh16, int K) {
  __shared__ f16 sAh[128 * 32], sAl[128 * 32], sBh[128 * 32], sBl[128 * 32];
  const int t = threadIdx.x;
  const int w = t >> 6, lane = t & 63, lm = lane & 15, q = lane >> 4;
  const int wr = w >> 1, wc = w & 1;
  const int n0 = blockIdx.x * 128, m0 = blockIdx.y * 128;
  f32x4 acc[4][4] = {};
  for (int k0 = 0; k0 < K; k0 += 32) {
    const f16* s0 = Ah + (size_t)m0 * K + k0;
    const f16* s1 = Al + (size_t)m0 * K + k0;
    const f16* s2 = Bth + (size_t)n0 * K + k0;
    const f16* s3 = Btl + (size_t)n0 * K + k0;
#pragma unroll
    for (int c = 0; c < 2; ++c) {
      int f = (c * 256 + t) * 8; int row = f >> 5, col = f & 31;
      size_t go = (size_t)row * K + col;
      gl_lds16(s0 + go, &sAh[f]);
      gl_lds16(s1 + go, &sAl[f]);
      gl_lds16(s2 + go, &sBh[f]);
      gl_lds16(s3 + go, &sBl[f]);
    }
    __syncthreads();
    f16x8 a_h[4], a_l[4], b_h[4], b_l[4];
#pragma unroll
    for (int mi = 0; mi < 4; ++mi) {
      int r = (wr * 64 + mi * 16 + lm) * 32 + q * 8;
      a_h[mi] = *(const f16x8*)&sAh[r];
      a_l[mi] = *(const f16x8*)&sAl[r];
    }
#pragma unroll
    for (int ni = 0; ni < 4; ++ni) {
      int r = (wc * 64 + ni * 16 + lm) * 32 + q * 8;
      b_h[ni] = *(const f16x8*)&sBh[r];
      b_l[ni] = *(const f16x8*)&sBl[r];
    }
#pragma unroll
    for (int mi = 0; mi < 4; ++mi)
#pragma unroll
      for (int ni = 0; ni < 4; ++ni) {
        acc[mi][ni] = MFMA(a_h[mi], b_h[ni], acc[mi][ni]);
        acc[mi][ni] = MFMA(a_h[mi], b_l[ni], acc[mi][ni]);
        acc[mi][ni] = MFMA(a_l[mi], b_h[ni], acc[mi][ni]);
      }
    __syncthreads();
  }
#pragma unroll
  for (int mi = 0; mi < 4; ++mi)
#pragma unroll
    for (int ni = 0; ni < 4; ++ni) {
      int nglob = n0 + wc * 64 + ni * 16;         // 16-aligned, wave-uniform segment
      int seg = nglob >> 10;
      int c = (nglob & 1023) + lm;                // column within segment
      const float* bp = (seg == 0) ? bq : (seg == 1) ? bk : bv;
      float bvv = bp[c];
#pragma unroll
      for (int r = 0; r < 4; ++r) {
        int grow = m0 + wr * 64 + mi * 16 + q * 4 + r;
        float v = acc[mi][ni][r] * ESC_PROJ + bvv;
        size_t o = (size_t)grow * 1024 + c;
        if (seg == 0) {
          Qf[o] = v;
          f16 hh, ll; splitf16(v * SQf, hh, ll); Qbh[o] = hh; Qbl[o] = ll;
        } else if (seg == 1) {
          Kf[o] = v;
          f16 hh, ll; splitf16(v * SQf, hh, ll); Kbh[o] = hh; Kbl[o] = ll;
        } else {
          Vh16[o] = (f16)(v * SVf);
        }
      }
    }
}

// ---------------- transpose V (f16): Vh16[b,l,D] -> Vt[bh*64+d][L] ----------------
__global__ __launch_bounds__(256) void tsplit_v(
    const f16* __restrict__ Vh16, f16* __restrict__ out) {
  __shared__ f16 ts[64][72];
  const int t = threadIdx.x;
  const int l0 = blockIdx.x * 64;
  const int bh = blockIdx.y, b = bh >> 4, h = bh & 15;
#pragma unroll
  for (int c = 0; c < 2; ++c) {
    int e = c * 256 + t; int row = e >> 3, cg = e & 7;
    *(uint4*)&ts[row][cg * 8] =
        *(const uint4*)&Vh16[((size_t)b * Ln + l0 + row) * Dn + h * DHn + cg * 8];
  }
  __syncthreads();
#pragma unroll
  for (int c = 0; c < 2; ++c) {
    int e = c * 256 + t; int drow = e >> 3, lg = e & 7;
    f16 tmp[8];
#pragma unroll
    for (int j = 0; j < 8; ++j) tmp[j] = ts[lg * 8 + j][drow];
    *(uint4*)&out[((size_t)bh * DHn + drow) * Ln + l0 + lg * 8] = *(uint4*)tmp;
  }
}

// ---------------- A-single MFMA GEMM (out proj): 128x64 tiles ----------------
__global__ __launch_bounds__(256, 4) void gemm_a1(
    const f16* __restrict__ A,
    const f16* __restrict__ Bth, const f16* __restrict__ Btl,
    const float* __restrict__ bias, float escale,
    float* __restrict__ Cf, int M, int N, int K) {
  __shared__ f16 sA[128 * 32], sBh[64 * 32], sBl[64 * 32];
  const int t = threadIdx.x;
  const int w = t >> 6, lane = t & 63, lm = lane & 15, q = lane >> 4;
  const int wr = w >> 1, wc = w & 1;
  const int n0 = blockIdx.x * 64, m0 = blockIdx.y * 128;
  f32x4 acc[4][2] = {};
  for (int k0 = 0; k0 < K; k0 += 32) {
    const f16* s0 = A + (size_t)m0 * K + k0;
    const f16* s2 = Bth + (size_t)n0 * K + k0;
    const f16* s3 = Btl + (size_t)n0 * K + k0;
#pragma unroll
    for (int c = 0; c < 2; ++c) {
      int f = (c * 256 + t) * 8; int row = f >> 5, col = f & 31;
      gl_lds16(s0 + (size_t)row * K + col, &sA[f]);
    }
    {
      int f = t * 8; int row = f >> 5, col = f & 31;
      gl_lds16(s2 + (size_t)row * K + col, &sBh[f]);
      gl_lds16(s3 + (size_t)row * K + col, &sBl[f]);
    }
    __syncthreads();
    f16x8 a_[4], b_h[2], b_l[2];
#pragma unroll
    for (int mi = 0; mi < 4; ++mi)
      a_[mi] = *(const f16x8*)&sA[(wr * 64 + mi * 16 + lm) * 32 + q * 8];
#pragma unroll
    for (int ni = 0; ni < 2; ++ni) {
      int r = (wc * 32 + ni * 16 + lm) * 32 + q * 8;
      b_h[ni] = *(const f16x8*)&sBh[r];
      b_l[ni] = *(const f16x8*)&sBl[r];
    }
#pragma unroll
    for (int mi = 0; mi < 4; ++mi)
#pragma unroll
      for (int ni = 0; ni < 2; ++ni) {
        acc[mi][ni] = MFMA(a_[mi], b_h[ni], acc[mi][ni]);
        acc[mi][ni] = MFMA(a_[mi], b_l[ni], acc[mi][ni]);
      }
    __syncthreads();
  }
#pragma unroll
  for (int mi = 0; mi < 4; ++mi)
#pragma unroll
    for (int ni = 0; ni < 2; ++ni) {
      int gcol = n0 + wc * 32 + ni * 16 + lm;
      float bvv = bias[gcol];
#pragma unroll
      for (int r = 0; r < 4; ++r) {
        int grow = m0 + wr * 64 + mi * 16 + q * 4 + r;
        Cf[(size_t)grow * N + gcol] = acc[mi][ni][r] * escale + bvv;
      }
    }
}

// ---------------- ksum[bh][d] += partial sums (grid (8, BH), atomic) ----------------
__global__ __launch_bounds__(256) void ksum_part(
    const f16* __restrict__ Kh, const f16* __restrict__ Kl, float* __restrict__ ksum) {
  __shared__ float red[4][64];
  const int t = threadIdx.x, d = t & 63, seg = t >> 6;
  const int bx = blockIdx.x, bh = blockIdx.y, b = bh >> 4, h = bh & 15;
  float s = 0.f;
  const int lbase = bx * 256 + seg * 64;
  for (int r = 0; r < 64; ++r) {
    size_t o = ((size_t)b * Ln + lbase + r) * Dn + h * DHn + d;
    s += (float)Kh[o] + (float)Kl[o];
  }
  red[seg][d] = s;
  __syncthreads();
  if (t < 64) atomicAdd(&ksum[bh * DHn + t], red[0][t] + red[1][t] + red[2][t] + red[3][t]);
}

// ---------------- stats: approx row max (MFMA, split) + spars = max - mean ----------------
__global__ __launch_bounds__(256, 2) void attn_stats_mfma(
    const f16* __restrict__ Qh, const f16* __restrict__ Ql,
    const f16* __restrict__ Kh, const f16* __restrict__ Kl,
    const float* __restrict__ ksum,
    float* __restrict__ row_max, float* __restrict__ spars) {
  __shared__ f16 sQh[128 * 64], sQl[128 * 64], sKh[128 * 64], sKl[128 * 64];
  __shared__ float redm[128][5];
  const int t = threadIdx.x;
  const int w = t >> 6, lane = t & 63, lm = lane & 15, q = lane >> 4;
  const int bh = blockIdx.y, b = bh >> 4, h = bh & 15;
  const int q0 = blockIdx.x * 128;
  const f16* qsh = Qh + ((size_t)b * Ln + q0) * Dn + h * DHn;
  const f16* qsl = Ql + ((size_t)b * Ln + q0) * Dn + h * DHn;
#pragma unroll
  for (int c = 0; c < 4; ++c) {
    int f = (c * 256 + t) * 8; int row = f >> 6, col = f & 63;
    size_t go = (size_t)row * Dn + col;
    gl_lds16(qsh + go, &sQh[f]);
    gl_lds16(qsl + go, &sQl[f]);
  }
  __syncthreads();
  f16x8 a_h[8][2], a_l[8][2];
#pragma unroll
  for (int mi = 0; mi < 8; ++mi)
#pragma unroll
    for (int ks = 0; ks < 2; ++ks) {
      int r = (mi * 16 + lm) * 64 + ks * 32 + q * 8;
      a_h[mi][ks] = *(const f16x8*)&sQh[r];
      a_l[mi][ks] = *(const f16x8*)&sQl[r];
    }
  float rmax[8][4];
#pragma unroll
  for (int mi = 0; mi < 8; ++mi)
#pragma unroll
    for (int r = 0; r < 4; ++r) rmax[mi][r] = -1e30f;

  for (int kt = 0; kt < Ln / 128; ++kt) {
    __syncthreads();
    const f16* ksh = Kh + ((size_t)b * Ln + kt * 128) * Dn + h * DHn;
    const f16* ksl = Kl + ((size_t)b * Ln + kt * 128) * Dn + h * DHn;
#pragma unroll
    for (int c = 0; c < 4; ++c) {
      int f = (c * 256 + t) * 8; int row = f >> 6, col = f & 63;
      size_t go = (size_t)row * Dn + col;
      gl_lds16(ksh + go, &sKh[f]);
      gl_lds16(ksl + go, &sKl[f]);
    }
    __syncthreads();
#pragma unroll
    for (int ni = 0; ni < 2; ++ni) {
      int bcol = (w * 2 + ni) * 16;
      f16x8 b_h[2], b_l[2];
#pragma unroll
      for (int ks = 0; ks < 2; ++ks) {
        int r = (bcol + lm) * 64 + ks * 32 + q * 8;
        b_h[ks] = *(const f16x8*)&sKh[r];
        b_l[ks] = *(const f16x8*)&sKl[r];
      }
#pragma unroll
      for (int mi = 0; mi < 8; ++mi) {
        f32x4 acc = {0.f, 0.f, 0.f, 0.f};
#pragma unroll
        for (int ks = 0; ks < 2; ++ks) {
          acc = MFMA(a_h[mi][ks], b_h[ks], acc);
          acc = MFMA(a_h[mi][ks], b_l[ks], acc);
          acc = MFMA(a_l[mi][ks], b_h[ks], acc);
        }
#pragma unroll
        for (int r = 0; r < 4; ++r) rmax[mi][r] = fmaxf(rmax[mi][r], acc[r]);
      }
    }
  }
#pragma unroll
  for (int mi = 0; mi < 8; ++mi)
#pragma unroll
    for (int r = 0; r < 4; ++r) {
      float v = rmax[mi][r];
      v = fmaxf(v, __shfl_xor(v, 1)); v = fmaxf(v, __shfl_xor(v, 2));
      v = fmaxf(v, __shfl_xor(v, 4)); v = fmaxf(v, __shfl_xor(v, 8));
      if (lm == 0) redm[mi * 16 + q * 4 + r][w] = v;
    }
  __syncthreads();
  if (t < 128) {
    float m = fmaxf(fmaxf(redm[t][0], redm[t][1]), fmaxf(redm[t][2], redm[t][3]));
    float dot = 0.f;
    const float* kp = ksum + bh * DHn;
#pragma unroll
    for (int d = 0; d < 64; ++d)
      dot += ((float)sQh[t * 64 + d] + (float)sQl[t * 64 + d]) * kp[d];
    row_max[(size_t)bh * Ln + q0 + t] = m * PSC;
    spars[(size_t)bh * Ln + q0 + t] = m * PSC - dot * (PSC / (float)Ln);
  }
}

// ---------------- bitonic sort, 1024 threads (1 pair per thread per step) ----------------
__global__ __launch_bounds__(1024) void topk_sort(
    const float* __restrict__ spars, int* __restrict__ top_idx, int* __restrict__ wrow) {
  __shared__ unsigned long long keys[Ln];   // 16 KB
  const int t = threadIdx.x;
  const int bh = blockIdx.x;
  for (int i = t; i < Ln; i += 1024) {
    unsigned u = __float_as_uint(spars[(size_t)bh * Ln + i]);
    u = (u & 0x80000000u) ? ~u : (u | 0x80000000u);
    u = ~u;
    keys[i] = ((unsigned long long)u << 32) | (unsigned)i;
  }
  __syncthreads();
  for (int k = 2; k <= Ln; k <<= 1) {
    for (int j = k >> 1; j > 0; j >>= 1) {
      int i = ((t & ~(j - 1)) << 1) | (t & (j - 1));
      int ixj = i | j;
      unsigned long long a = keys[i], bb = keys[ixj];
      bool up = ((i & k) == 0);
      if ((a > bb) == up) { keys[i] = bb; keys[ixj] = a; }
      __syncthreads();
    }
  }
  for (int u = t; u < Un - 8; u += 1024)
    top_idx[(size_t)bh * Un + u] = (int)(keys[u] & 0xFFFFFFFFu);
  if (t < 16) wrow[bh * 16 + t] = (int)(keys[Un - 8 + t] & 0xFFFFFFFFu);
}

// ---------------- exact fp32 sparsity for one window row per block ----------------
__global__ __launch_bounds__(256) void refine_rows(
    const float* __restrict__ Qf, const float* __restrict__ Kf,
    const int* __restrict__ wrow, float* __restrict__ spx) {
  __shared__ float qs[64];
  __shared__ float redm[4], reds[4];
  const int t = threadIdx.x;
  const int j = blockIdx.x, bh = blockIdx.y, b = bh >> 4, h = bh & 15;
  const int qi = wrow[bh * 16 + j];
  if (t < 64) qs[t] = Qf[((size_t)b * Ln + qi) * Dn + h * DHn + t];
  __syncthreads();
  float mx = -1e30f, sm = 0.f;
  for (int ki = t; ki < Ln; ki += 256) {
    const float* kp = &Kf[((size_t)b * Ln + ki) * Dn + h * DHn];
    float s = 0.f;
#pragma unroll
    for (int d0 = 0; d0 < 64; d0 += 4) {
      float4 k4 = *(const float4*)&kp[d0];
      s = fmaf(k4.x, qs[d0], s);
      s = fmaf(k4.y, qs[d0 + 1], s);
      s = fmaf(k4.z, qs[d0 + 2], s);
      s = fmaf(k4.w, qs[d0 + 3], s);
    }
    mx = fmaxf(mx, s); sm += s;
  }
  const int w = t >> 6, lane = t & 63;
#pragma unroll
  for (int off = 1; off < 64; off <<= 1) {
    mx = fmaxf(mx, __shfl_xor(mx, off));
    sm += __shfl_xor(sm, off);
  }
  if (lane == 0) { redm[w] = mx; reds[w] = sm; }
  __syncthreads();
  if (t == 0) {
    float m = fmaxf(fmaxf(redm[0], redm[1]), fmaxf(redm[2], redm[3]));
    float s = reds[0] + reds[1] + reds[2] + reds[3];
    spx[bh * 16 + j] = SCALE * (m - s * (1.0f / (float)Ln));
  }
}

// ---------------- pick top-8 of the 16 window rows (exact values) ----------------
__global__ __launch_bounds__(64) void topk_final(
    const float* __restrict__ spx, const int* __restrict__ wrow,
    int* __restrict__ top_idx) {
  const int bh = blockIdx.x;
  if (threadIdx.x != 0) return;
  float v[16]; int r[16];
#pragma unroll
  for (int j = 0; j < 16; ++j) { v[j] = spx[bh * 16 + j]; r[j] = wrow[bh * 16 + j]; }
  unsigned taken = 0;
  for (int s = 0; s < 8; ++s) {
    int best = -1;
    for (int j = 0; j < 16; ++j) {
      if (taken & (1u << j)) continue;
      if (best < 0 || v[j] > v[best] || (v[j] == v[best] && r[j] < r[best])) best = j;
    }
    taken |= 1u << best;
    top_idx[(size_t)bh * Un + (Un - 8) + s] = r[best];
  }
}

// ------- selected-row attention, key-split x2: partial O (unnormalized) + denom -------
// grid (ceil(U/64), 2*BH); half = by&1 covers keys [half*1024, half*1024+1024)
__global__ __launch_bounds__(256, 4) void attn_sel_part(
    const f16* __restrict__ Qh, const f16* __restrict__ Kh,
    const f16* __restrict__ Vth,
    const int* __restrict__ topi, const float* __restrict__ row_max,
    float* __restrict__ pO, float* __restrict__ pD) {
  __shared__ f16 sK[64 * 64], sV[64 * 64];
  __shared__ f16 sQP[64 * 80];   // Q staged (stride 80), then P (stride 80)
  __shared__ float rmL[64];
  __shared__ int qxL[64];
  __shared__ float dred[64][5];
  const int t = threadIdx.x;
  const int w = t >> 6, lane = t & 63, lm = lane & 15, q = lane >> 4;
  const int half = blockIdx.y & 1, bh = blockIdx.y >> 1, b = bh >> 4, h = bh & 15;
  const int u0 = blockIdx.x * 64;
  const int nrows = (Un - u0 < 64) ? (Un - u0) : 64;
  if (t < 64) {
    int qi = topi[(size_t)bh * Un + ((t < nrows) ? (u0 + t) : 0)];
    qxL[t] = qi;
    rmL[t] = row_max[(size_t)bh * Ln + qi];
  }
  __syncthreads();
#pragma unroll
  for (int c = 0; c < 2; ++c) {
    int f = (c * 256 + t) * 8; int row = f >> 6, col = f & 63;
    size_t go = ((size_t)b * Ln + qxL[row]) * Dn + h * DHn + col;
    *(uint4*)&sQP[row * 80 + col] = *(const uint4*)&Qh[go];
  }
  __syncthreads();
  f16x8 aq[4][2];
#pragma unroll
  for (int mi = 0; mi < 4; ++mi)
#pragma unroll
    for (int ks = 0; ks < 2; ++ks)
      aq[mi][ks] = *(const f16x8*)&sQP[(mi * 16 + lm) * 80 + ks * 32 + q * 8];
  f32x4 oacc[4] = {};
  float dacc[4][4] = {};

  const f16* kbase = Kh + (size_t)b * Ln * Dn + h * DHn;
  const f16* vbase = Vth + (size_t)bh * DHn * Ln;
  for (int kt = 0; kt < 16; ++kt) {
    const int l0 = half * 1024 + kt * 64;
    __syncthreads();
#pragma unroll
    for (int c = 0; c < 2; ++c) {
      int f = (c * 256 + t) * 8; int row = f >> 6, col = f & 63;
      gl_lds16(kbase + (size_t)(l0 + row) * Dn + col, &sK[f]);
      gl_lds16(vbase + (size_t)row * Ln + l0 + col, &sV[f]);
    }
    __syncthreads();
    f16x8 kb[2];
#pragma unroll
    for (int ks = 0; ks < 2; ++ks)
      kb[ks] = *(const f16x8*)&sK[(w * 16 + lm) * 64 + ks * 32 + q * 8];
#pragma unroll
    for (int mi = 0; mi < 4; ++mi) {
      f32x4 acc = {0.f, 0.f, 0.f, 0.f};
      acc = MFMA(aq[mi][0], kb[0], acc);
      acc = MFMA(aq[mi][1], kb[1], acc);
#pragma unroll
      for (int r = 0; r < 4; ++r) {
        int row = mi * 16 + q * 4 + r;
        float p = __expf(acc[r] * PSC - rmL[row]);
        dacc[mi][r] += p;
        sQP[row * 80 + w * 16 + lm] = (f16)(p * SPf);
      }
    }
    __syncthreads();
    f16x8 vb[2];
#pragma unroll
    for (int ks = 0; ks < 2; ++ks)
      vb[ks] = *(const f16x8*)&sV[(w * 16 + lm) * 64 + ks * 32 + q * 8];
#pragma unroll
    for (int mi = 0; mi < 4; ++mi) {
#pragma unroll
      for (int ks = 0; ks < 2; ++ks) {
        f16x8 pf = *(const f16x8*)&sQP[(mi * 16 + lm) * 80 + ks * 32 + q * 8];
        oacc[mi] = MFMA(pf, vb[ks], oacc[mi]);
      }
    }
  }
#pragma unroll
  for (int mi = 0; mi < 4; ++mi)
#pragma unroll
    for (int r = 0; r < 4; ++r) {
      float v = dacc[mi][r];
      v += __shfl_xor(v, 1); v += __shfl_xor(v, 2);
      v += __shfl_xor(v, 4); v += __shfl_xor(v, 8);
      if (lm == 0) dred[mi * 16 + q * 4 + r][w] = v;
    }
  __syncthreads();
  const size_t pbase = ((size_t)half * BHn + bh) * 1280 + u0;
  if (t < 64)
    pD[pbase + t] = dred[t][0] + dred[t][1] + dred[t][2] + dred[t][3];
#pragma unroll
  for (int mi = 0; mi < 4; ++mi)
#pragma unroll
    for (int r = 0; r < 4; ++r) {
      int row = mi * 16 + q * 4 + r;
      pO[(pbase + row) * 64 + w * 16 + lm] = oacc[mi][r];
    }
}

// ---------------- combine halves, normalize, scatter to AOh ----------------
__global__ __launch_bounds__(256) void attn_combine(
    const float* __restrict__ pO, const float* __restrict__ pD,
    const int* __restrict__ topi, f16* __restrict__ AOh) {
  const int t = threadIdx.x;
  const int u0 = blockIdx.x * 64, bh = blockIdx.y, b = bh >> 4, h = bh & 15;
  const int nrows = (Un - u0 < 64) ? (Un - u0) : 64;
  const int row = t >> 2, pg = t & 3;
  if (row >= nrows) return;
  int qi = topi[(size_t)bh * Un + u0 + row];
  size_t i0 = (size_t)bh * 1280 + u0 + row;
  size_t i1 = (size_t)BHn * 1280 + i0;
  float dinv = 1.0f / (pD[i0] + pD[i1]);
  const float* p0 = &pO[i0 * 64 + pg * 16];
  const float* p1 = &pO[i1 * 64 + pg * 16];
  f16 buf[16];
#pragma unroll
  for (int c = 0; c < 4; ++c) {
    float4 a = *(const float4*)&p0[c * 4];
    float4 bb = *(const float4*)&p1[c * 4];
    buf[c * 4 + 0] = (f16)((a.x + bb.x) * dinv);
    buf[c * 4 + 1] = (f16)((a.y + bb.y) * dinv);
    buf[c * 4 + 2] = (f16)((a.z + bb.z) * dinv);
    buf[c * 4 + 3] = (f16)((a.w + bb.w) * dinv);
  }
  f16* dst = &AOh[((size_t)b * Ln + qi) * Dn + h * DHn + pg * 16];
  *(uint4*)&dst[0] = *(uint4*)&buf[0];
  *(uint4*)&dst[8] = *(uint4*)&buf[8];
}

extern "C" void kernel_launch(void* const* d_in, const int* in_sizes, int n_in,
                              void* d_out, int out_size, void* d_ws, size_t ws_size,
                              hipStream_t stream) {
  (void)in_sizes; (void)n_in; (void)out_size; (void)ws_size;
  const float* x  = (const float*)d_in[0];
  const float* Wq = (const float*)d_in[1];
  const float* bq = (const float*)d_in[2];
  const float* Wk = (const float*)d_in[3];
  const float* bk = (const float*)d_in[4];
  const float* Wv = (const float*)d_in[5];
  const float* bv = (const float*)d_in[6];
  const float* Wo = (const float*)d_in[7];
  const float* bo = (const float*)d_in[8];
  float* out = (float*)d_out;

  uint8_t* p = (uint8_t*)d_ws;
  const size_t NE = (size_t)Bn * Ln * Dn;          // 4 Mi elements
  f16* xh = (f16*)p;  p += NE * 2;
  f16* xl = (f16*)p;  p += NE * 2;
  f16* Wt_h = (f16*)p; p += (size_t)4096 * Dn * 2;   // rows 0-3071: QKV cat; 3072-4095: Wo
  f16* Wt_l = (f16*)p; p += (size_t)4096 * Dn * 2;
  f16* Qbh = (f16*)p; p += NE * 2;
  f16* Qbl = (f16*)p; p += NE * 2;
  f16* Kbh = (f16*)p; p += NE * 2;
  f16* Kbl = (f16*)p; p += NE * 2;
  float* Qf = (float*)p;  p += NE * 4;
  float* Kf = (float*)p;  p += NE * 4;
  f16* Vh16 = (f16*)p; p += NE * 2;
  f16* Vth  = (f16*)p; p += NE * 2;
  float* rowmax = (float*)p; p += (size_t)BHn * Ln * 4;
  float* spars  = (float*)p; p += (size_t)BHn * Ln * 4;
  float* ksum   = (float*)p; p += (size_t)BHn * DHn * 4;
  int* topi     = (int*)p;   p += (size_t)BHn * Un * 4;
  int* wrow     = (int*)p;   p += (size_t)BHn * 16 * 4;
  float* spx    = (float*)p; p += (size_t)BHn * 16 * 4;
  float* pD     = (float*)p; p += (size_t)2 * BHn * 1280 * 4;
  // pO (20.97 MB) aliases Qf+Kf (32 MB, dead after refine_rows)
  float* pO = Qf;
  f16* AOh = xh;   // alias: x split dead after QKV GEMM

  dim3 blk(256);
  hipLaunchKernelGGL(split_kernel, dim3((int)(NE / 4 / 256)), blk, 0, stream, x, xh, xl, (int)(NE / 4));
  hipLaunchKernelGGL(tsplit_w4, dim3(16, 16, 4), blk, 0, stream, Wq, Wk, Wv, Wo, Wt_h, Wt_l);
  hipLaunchKernelGGL(gemm_qkv, dim3(24, 32), blk, 0, stream, xh, xl, Wt_h, Wt_l,
                     bq, bk, bv, Qf, Qbh, Qbl, Kf, Kbh, Kbl, Vh16, Dn);
  hipLaunchKernelGGL(tsplit_v, dim3(Ln / 64, BHn), blk, 0, stream, Vh16, Vth);
  hipMemsetAsync(ksum, 0, (size_t)BHn * DHn * 4, stream);
  hipLaunchKernelGGL(ksum_part, dim3(8, BHn), blk, 0, stream, Kbh, Kbl, ksum);
  hipLaunchKernelGGL(attn_stats_mfma, dim3(Ln / 128, BHn), blk, 0, stream,
                     Qbh, Qbl, Kbh, Kbl, ksum, rowmax, spars);
  hipLaunchKernelGGL(topk_sort, dim3(BHn), dim3(1024), 0, stream, spars, topi, wrow);
  hipLaunchKernelGGL(refine_rows, dim3(16, BHn), blk, 0, stream, Qf, Kf, wrow, spx);
  hipLaunchKernelGGL(topk_final, dim3(BHn), dim3(64), 0, stream, spx, wrow, topi);
  hipMemsetAsync(AOh, 0, NE * 2, stream);
  hipLaunchKernelGGL(attn_sel_part, dim3((Un + 63) / 64, 2 * BHn), blk, 0, stream,
                     Qbh, Kbh, Vth, topi, rowmax, pO, pD);
  hipLaunchKernelGGL(attn_combine, dim3((Un + 63) / 64, BHn), blk, 0, stream,
                     pO, pD, topi, AOh);
  hipLaunchKernelGGL(gemm_a1, dim3(16, 32), blk, 0, stream, AOh,
                     Wt_h + (size_t)3072 * Dn, Wt_l + (size_t)3072 * Dn, bo,
                     ESC_OUT, out, Bn * Ln, Dn, Dn);
}